// Round 14
// baseline (153.913 us; speedup 1.0000x reference)
//
#include <hip/hip_runtime.h>
#include <math.h>
#include <stdint.h>

#define CDIM 128
#define NTOT 4096
#define LOG2E 1.44269504f
#define NZ 8          // split-K factor

typedef _Float16 f16x8 __attribute__((ext_vector_type(8)));  // 8 fp16 (4 VGPRs)
typedef _Float16 f16x4 __attribute__((ext_vector_type(4)));  // 4 fp16 (2 VGPRs)
typedef float floatx4 __attribute__((ext_vector_type(4)));   // MFMA accumulator

static __device__ __forceinline__ floatx4 mfma16(f16x8 a, f16x8 b, floatx4 c) {
    return __builtin_amdgcn_mfma_f32_16x16x32_f16(a, b, c, 0, 0, 0);
}
static __device__ __forceinline__ floatx4 mfma16k16(f16x4 a, f16x4 b, floatx4 c) {
    return __builtin_amdgcn_mfma_f32_16x16x16f16(a, b, c, 0, 0, 0);
}
static __device__ __forceinline__ unsigned short f2h(float f) {
    _Float16 h = (_Float16)f;
    return __builtin_bit_cast(unsigned short, h);
}
static __device__ __forceinline__ float h2f(unsigned short u) {
    return (float)__builtin_bit_cast(_Float16, u);
}
// raw v_exp_f32 (exp2). exp2f() libm adds denormal fixup VALU (R9 regression).
static __device__ __forceinline__ float fexp2(float x) {
#if __has_builtin(__builtin_amdgcn_exp2f)
    return __builtin_amdgcn_exp2f(x);
#else
    return exp2f(x);
#endif
}

// XOR-swizzled LDS addressing, rows of 128 ush (16 chunks of 16 B):
// chunk cc stored at linear slot cc ^ (row & 15).
#define SWZ(row, cc) ((((row) << 7)) + ((((cc) ^ ((row) & 15))) << 3))
// rows of 64 ush (8 chunks of 16 B): chunk cc at slot cc ^ (row & 7).
#define SWZ8(row, cc) ((((row) << 6)) + ((((cc) ^ ((row) & 7))) << 3))

// async global->LDS, 16 B per lane. LDS dest = wave-uniform base + lane*16
// (linear); swizzle realized by inverse-permuting the per-lane GLOBAL source.
static __device__ __forceinline__ void gload_lds16(const void* g, void* l) {
    __builtin_amdgcn_global_load_lds(
        (const __attribute__((address_space(1))) void*)g,
        (__attribute__((address_space(3))) void*)l, 16, 0, 0);
}

// ---------------------------------------------------------------------------
// Fused q/k/v projection (R7/R10-best single-phase staging; unchanged).
// q output scaled by LOG2E in f32 (exact) for base-2 softmax.
// x: [4][128][4096] fp32. Outputs fp16: qo, ko: [b][n][c]; vo: [b][c][n].
// grid (64 n-tiles, 4 batches, 2 o-halves), 256 threads / 4 waves.
// ---------------------------------------------------------------------------
__global__ __launch_bounds__(256) void qkv_proj_kernel(
    const float* __restrict__ x,
    const float* __restrict__ Wq, const float* __restrict__ Wk,
    const float* __restrict__ Wv,
    const float* __restrict__ bq, const float* __restrict__ bk,
    const float* __restrict__ bv,
    unsigned short* __restrict__ qo, unsigned short* __restrict__ ko,
    unsigned short* __restrict__ vo)
{
    __shared__ __align__(16) unsigned short Xs[64][136];      // [n][c] fp16
    __shared__ __align__(16) unsigned short Ws[3][64][136];   // [s][o-half][c] fp16

    const int t = threadIdx.x, b = blockIdx.y, n0 = blockIdx.x * 64;
    const int zo = blockIdx.z * 64;
    const int w = t >> 6, quad = (t >> 4) & 3, l15 = t & 15;

    // stage x tile with transpose-on-store: thread covers 4n x 8c
    {
        const int n = (t & 15) * 4;
        const int c = (t >> 4) * 8;
        float4 xr[8];
        #pragma unroll
        for (int j = 0; j < 8; ++j)
            xr[j] = *(const float4*)&x[((size_t)b * CDIM + c + j) * NTOT + n0 + n];
        #pragma unroll
        for (int k = 0; k < 4; ++k) {
            ushort4 ulo, uhi;
            ulo.x = f2h(((const float*)&xr[0])[k]);
            ulo.y = f2h(((const float*)&xr[1])[k]);
            ulo.z = f2h(((const float*)&xr[2])[k]);
            ulo.w = f2h(((const float*)&xr[3])[k]);
            uhi.x = f2h(((const float*)&xr[4])[k]);
            uhi.y = f2h(((const float*)&xr[5])[k]);
            uhi.z = f2h(((const float*)&xr[6])[k]);
            uhi.w = f2h(((const float*)&xr[7])[k]);
            *(ushort4*)&Xs[n + k][c]     = ulo;
            *(ushort4*)&Xs[n + k][c + 4] = uhi;
        }
    }
    // stage all three W o-halves (f32 -> f16): thread covers 1 o-row x 32c per s
    {
        const int o = t >> 2, ch = (t & 3) * 32;
        #pragma unroll
        for (int s = 0; s < 3; ++s) {
            const float* W = (s == 0) ? Wq : (s == 1) ? Wk : Wv;
            #pragma unroll
            for (int i = 0; i < 8; ++i) {
                float4 f4 = *(const float4*)&W[(size_t)(zo + o) * CDIM + ch + i * 4];
                ushort4 u = { f2h(f4.x), f2h(f4.y), f2h(f4.z), f2h(f4.w) };
                *(ushort4*)&Ws[s][o][ch + i * 4] = u;
            }
        }
    }
    __syncthreads();   // the ONLY barrier

    f16x8 xf[4];
    #pragma unroll
    for (int f = 0; f < 4; ++f)
        xf[f] = *(const f16x8*)&Xs[w * 16 + l15][f * 32 + quad * 8];

    // q, k: C[o][n], A = W, B = X. q gets the LOG2E scale (f32, exact).
    #pragma unroll
    for (int s = 0; s < 2; ++s) {
        const float* bias = s ? bk : bq;
        unsigned short* dst = s ? ko : qo;
        const float sc = (s == 0) ? LOG2E : 1.0f;
        #pragma unroll
        for (int ot = 0; ot < 4; ++ot) {
            floatx4 acc = (floatx4){0.f, 0.f, 0.f, 0.f};
            #pragma unroll
            for (int f = 0; f < 4; ++f) {
                f16x8 aW = *(const f16x8*)&Ws[s][ot * 16 + l15][f * 32 + quad * 8];
                acc = mfma16(aW, xf[f], acc);
            }
            const int ob = zo + ot * 16 + quad * 4;
            ushort4 u;
            u.x = f2h((acc[0] + bias[ob + 0]) * sc);
            u.y = f2h((acc[1] + bias[ob + 1]) * sc);
            u.z = f2h((acc[2] + bias[ob + 2]) * sc);
            u.w = f2h((acc[3] + bias[ob + 3]) * sc);
            *(ushort4*)&dst[((size_t)b * NTOT + n0 + w * 16 + l15) * CDIM + ob] = u;
        }
    }
    // v: C'[n][o], A = X, B = W
    #pragma unroll
    for (int ot = 0; ot < 4; ++ot) {
        floatx4 acc = (floatx4){0.f, 0.f, 0.f, 0.f};
        #pragma unroll
        for (int f = 0; f < 4; ++f) {
            f16x8 bW = *(const f16x8*)&Ws[2][ot * 16 + l15][f * 32 + quad * 8];
            acc = mfma16(xf[f], bW, acc);
        }
        const int o = zo + ot * 16 + l15;
        const float bv_ = bv[o];
        ushort4 u;
        u.x = f2h(acc[0] + bv_); u.y = f2h(acc[1] + bv_);
        u.z = f2h(acc[2] + bv_); u.w = f2h(acc[3] + bv_);
        *(ushort4*)&vo[((size_t)b * CDIM + o) * NTOT + n0 + w * 16 + quad * 4] = u;
    }
}

// ---------------------------------------------------------------------------
// Flash attention v11: P NEVER TOUCHES LDS. QK's accT layout (lane l15+16q
// holds P[j=jt*16+4q+r][i=l15]) is bit-identical to the B-operand of
// mfma_f32_16x16x16_f16 with k-offset jt*16 -- so the cvt_pkrtz-packed
// pu[nt][jt] feeds PV directly from registers (zero cross-lane movement).
// Deletes Ps/WP/RB -> LDS = K dbuf 32 + V triple 48 = 80 KB -> 2 blocks/CU:
// 16 waves/CU in 2 independent gangs whose phase drift overlaps one gang's
// MFMA with the other's softmax VALU. Split-K(8), KT=64, 8 iters; R13's
// single-barrier V-triple schedule and vmcnt ledger unchanged.
// grid (512) flat w/ bijective XCD swizzle. Ms stats in log2 domain.
// ---------------------------------------------------------------------------
__global__ __launch_bounds__(512) void attn_kernel(
    const unsigned short* __restrict__ qg,
    const unsigned short* __restrict__ kg,
    const unsigned short* __restrict__ vg,
    unsigned short* __restrict__ Op,
    float* __restrict__ Ms, float* __restrict__ Ls)
{
    __shared__ __align__(16) unsigned short Kb[2][64 * 128];   // 16 KB each
    __shared__ __align__(16) unsigned short Vb[3][128 * 64];   // 16 KB each

    const int t = threadIdx.x;                        // 0..511
    const int w = t >> 6, quad = (t >> 4) & 3, l15 = t & 15;

    const int bid = blockIdx.x;                       // 512
    const int swz = ((bid & 7) << 6) | (bid >> 3);    // bijective, 64/XCD chunks
    const int gidx = swz >> 4;            // 0..31 = (b,z) group
    const int b = gidx & 3;
    const int z = gidx >> 2;              // 0..7
    const int i0 = (swz & 15) * 256;
    const int jbase = z * (NTOT / NZ);    // 512 keys per block
    const size_t vbase = (size_t)b * CDIM * NTOT;

    // Q B-fragments direct from global (already LOG2E-scaled by qkv)
    f16x8 bQ[2][4];
    #pragma unroll
    for (int nt = 0; nt < 2; ++nt) {
        const size_t qrow = ((size_t)b * NTOT + i0 + w * 32 + nt * 16 + l15) * CDIM;
        #pragma unroll
        for (int f = 0; f < 4; ++f)
            bQ[nt][f] = *(const f16x8*)&qg[qrow + f * 32 + quad * 8];
    }

    // K tile [64 j][128 c] = 1024 chunks -> 2 per thread (512 thr).
    auto stageK = [&](unsigned short* Kd, int j0) {
        const size_t kbase = ((size_t)b * NTOT + j0) * CDIM;
        #pragma unroll
        for (int r = 0; r < 2; ++r) {
            const int flat = r * 512 + t;
            const int ldsoff = (r * 512 + (t & ~63)) * 8;  // wave-uniform, ush
            const int krow = flat >> 4, kcc = flat & 15;
            gload_lds16(&kg[kbase + (size_t)krow * CDIM + ((kcc ^ (krow & 15)) << 3)],
                        &Kd[ldsoff]);
        }
    };
    // V tile [128 d][64 j] = 1024 chunks -> 2 per thread.
    auto stageV = [&](unsigned short* Vd, int j0) {
        const size_t vrow0 = vbase + j0;
        #pragma unroll
        for (int r = 0; r < 2; ++r) {
            const int flat = r * 512 + t;
            const int ldsoff = (r * 512 + (t & ~63)) * 8;
            const int vrow = flat >> 3, vcc = flat & 7;
            gload_lds16(&vg[vrow0 + (size_t)vrow * NTOT + ((vcc ^ (vrow & 7)) << 3)],
                        &Vd[ldsoff]);
        }
    };

    floatx4 accO[2][8];   // [nt][dt]
    #pragma unroll
    for (int nt = 0; nt < 2; ++nt)
        #pragma unroll
        for (int dt = 0; dt < 8; ++dt) accO[nt][dt] = (floatx4){0.f, 0.f, 0.f, 0.f};
    float m_run[2] = {-INFINITY, -INFINITY};   // log2 domain
    float l_part[2] = {0.f, 0.f};

    floatx4 accT[2][4];
    uint2 pu[2][4];       // packed P(i); doubles as PV's B-operand next iter

    auto QK = [&](const unsigned short* Kd) {
        #pragma unroll
        for (int nt = 0; nt < 2; ++nt)
            #pragma unroll
            for (int jt = 0; jt < 4; ++jt) accT[nt][jt] = (floatx4){0.f, 0.f, 0.f, 0.f};
        __builtin_amdgcn_s_setprio(1);
        #pragma unroll
        for (int jt = 0; jt < 4; ++jt)
            #pragma unroll
            for (int f = 0; f < 4; ++f) {
                f16x8 aK = *(const f16x8*)&Kd[SWZ(jt * 16 + l15, f * 4 + quad)];
                accT[0][jt] = mfma16(aK, bQ[0][f], accT[0][jt]);
                accT[1][jt] = mfma16(aK, bQ[1][f], accT[1][jt]);
            }
        __builtin_amdgcn_s_setprio(0);
    };
    // PV: accO^T[d][i] += V·P^T via K=16 MFMA; B-operand = pu (in-register).
    // aV = V[d = dt*16 + l15][j = jt*16 + 4*quad + 0..3] (8 B), reused 2x (nt).
    auto PV = [&](const unsigned short* Vd) {
        __builtin_amdgcn_s_setprio(1);
        #pragma unroll
        for (int dt = 0; dt < 8; ++dt)
            #pragma unroll
            for (int jt = 0; jt < 4; ++jt) {
                f16x4 aV = *(const f16x4*)
                    &Vd[SWZ8(dt * 16 + l15, 2 * jt + (quad >> 1)) + (quad & 1) * 4];
                accO[0][dt] = mfma16k16(aV, __builtin_bit_cast(f16x4, pu[0][jt]),
                                        accO[0][dt]);
                accO[1][dt] = mfma16k16(aV, __builtin_bit_cast(f16x4, pu[1][jt]),
                                        accO[1][dt]);
            }
        __builtin_amdgcn_s_setprio(0);
    };
    auto SM = [&]() {   // base-2 online softmax, defer-max (THR = 8*log2e)
        #pragma unroll
        for (int nt = 0; nt < 2; ++nt) {
            float tm = accT[nt][0][0];
            #pragma unroll
            for (int jt = 0; jt < 4; ++jt)
                #pragma unroll
                for (int r = 0; r < 4; ++r) tm = fmaxf(tm, accT[nt][jt][r]);
            tm = fmaxf(tm, __shfl_xor(tm, 16));
            tm = fmaxf(tm, __shfl_xor(tm, 32));
            if (__ballot(tm > m_run[nt] + 11.5416f)) {
                const float m_new = fmaxf(m_run[nt], tm);
                const float alpha = fexp2(m_run[nt] - m_new);   // 0 on first tile
                m_run[nt] = m_new;
                l_part[nt] *= alpha;
                #pragma unroll
                for (int dt = 0; dt < 8; ++dt) {
                    accO[nt][dt][0] *= alpha; accO[nt][dt][1] *= alpha;
                    accO[nt][dt][2] *= alpha; accO[nt][dt][3] *= alpha;
                }
            }
            const float mcur = m_run[nt];
            float ps = 0.f;
            #pragma unroll
            for (int jt = 0; jt < 4; ++jt) {
                float p0 = fexp2(accT[nt][jt][0] - mcur);
                float p1 = fexp2(accT[nt][jt][1] - mcur);
                float p2 = fexp2(accT[nt][jt][2] - mcur);
                float p3 = fexp2(accT[nt][jt][3] - mcur);
                ps += (p0 + p1) + (p2 + p3);
                pu[nt][jt].x = __builtin_bit_cast(unsigned int,
                                   __builtin_amdgcn_cvt_pkrtz(p0, p1));
                pu[nt][jt].y = __builtin_bit_cast(unsigned int,
                                   __builtin_amdgcn_cvt_pkrtz(p2, p3));
            }
            l_part[nt] += ps;
        }
    };

    stageK(Kb[0], jbase);
    stageV(Vb[0], jbase);
    unsigned short *Kc = Kb[0], *Kn = Kb[1];
    unsigned short *Vprev = Vb[0], *Vcur = Vb[1], *Vnext = Vb[2];

    // ---- iter 0 (peeled): no PV ----
    asm volatile("s_waitcnt vmcnt(0) lgkmcnt(0)" ::: "memory");
    __builtin_amdgcn_s_barrier();
    stageK(Kn, jbase + 64);
    stageV(Vcur, jbase + 64);     // V[1] -> Vb[1]
    QK(Kc);
    SM();                          // -> pu(0)
    { unsigned short* tp = Kc; Kc = Kn; Kn = tp; }

    // ---- iters 1..6: ONE barrier per iter ----
    for (int it = 1; it <= 6; ++it) {
        // (A) vmcnt(2): forces K[it] + V[it-1] landed (oldest); V[it]'s 2
        // loads (newest) may fly. Barrier -> true for all waves; V[it-2]'s
        // buffer (Vnext) dead everywhere.
        asm volatile("s_waitcnt vmcnt(2) lgkmcnt(0)" ::: "memory");
        __builtin_amdgcn_s_barrier();
        stageK(Kn, jbase + (it + 1) * 64);      // K[it+1]
        stageV(Vnext, jbase + (it + 1) * 64);   // V[it+1] into V[it-2]'s buffer
        QK(Kc);                                 // MFMA: K[it] x Q
        PV(Vprev);                              // MFMA: V[it-1] x P[it-1] (reg P)
        SM();                                   // VALU: softmax[it] -> pu(it)
        { unsigned short* tp = Kc; Kc = Kn; Kn = tp; }
        { unsigned short* tv = Vprev; Vprev = Vcur; Vcur = Vnext; Vnext = tv; }
    }

    // ---- iter 7 (peeled): no staging ----
    asm volatile("s_waitcnt vmcnt(2) lgkmcnt(0)" ::: "memory");
    __builtin_amdgcn_s_barrier();
    QK(Kc);
    PV(Vprev);                                  // V[6], pu(6)
    SM();                                       // -> pu(7)
    // epilogue: all waves' V[7] staging landed
    asm volatile("s_waitcnt vmcnt(0) lgkmcnt(0)" ::: "memory");
    __builtin_amdgcn_s_barrier();
    PV(Vcur);                                   // V[7], pu(7)

    // final l over quads; store normalized partials + stats (Ms in log2 domain)
    #pragma unroll
    for (int nt = 0; nt < 2; ++nt) {
        float lf = l_part[nt];
        lf += __shfl_xor(lf, 16);
        lf += __shfl_xor(lf, 32);
        const float inv = 1.0f / lf;
        const size_t orow =
            (((size_t)z * 4 + b) * NTOT + i0 + w * 32 + nt * 16 + l15) * CDIM;
        #pragma unroll
        for (int dt = 0; dt < 8; ++dt) {
            ushort4 u;
            u.x = f2h(accO[nt][dt][0] * inv); u.y = f2h(accO[nt][dt][1] * inv);
            u.z = f2h(accO[nt][dt][2] * inv); u.w = f2h(accO[nt][dt][3] * inv);
            *(ushort4*)&Op[orow + dt * 16 + quad * 4] = u;
        }
        if (quad == 0) {
            const int idx = (z * 4 + b) * NTOT + i0 + w * 32 + nt * 16 + l15;
            Ms[idx] = m_run[nt];
            Ls[idx] = lf;
        }
    }
}

// ---------------------------------------------------------------------------
// Output projection + residual with FUSED split-K(8) combine (base-2 merge;
// R11-verified). Op: [8][b][n][128] fp16 partials, Ms/Ls: [8][b*n].
// grid (64, 4, 2 o-halves), 256 threads.
// ---------------------------------------------------------------------------
__global__ __launch_bounds__(256) void out_proj_kernel(
    const unsigned short* __restrict__ Op,
    const float* __restrict__ Ms, const float* __restrict__ Ls,
    const float* __restrict__ Wo, const float* __restrict__ bo,
    const float* __restrict__ x, float* __restrict__ out)
{
    __shared__ __align__(16) unsigned short As[64][136];  // [n][c] merged
    __shared__ __align__(16) unsigned short Ws[64][136];  // [o-half][c]

    const int t = threadIdx.x, b = blockIdx.y, n0 = blockIdx.x * 64;
    const int zo = blockIdx.z * 64;
    const int w = t >> 6, quad = (t >> 4) & 3, l15 = t & 15;

    const size_t PER = (size_t)NTOT * 4 * CDIM;   // elements per key-split

    #pragma unroll
    for (int r = 0; r < 4; ++r) {   // stage merged ao tile
        int flat = r * 256 + t;
        int row = flat >> 4, c16 = (flat & 15) * 8;
        const int bn = b * NTOT + n0 + row;

        float m[NZ], lw[NZ];
        float M = -INFINITY;
        #pragma unroll
        for (int zz = 0; zz < NZ; ++zz) { m[zz] = Ms[bn + zz * 16384]; M = fmaxf(M, m[zz]); }
        float wsum = 0.f;
        #pragma unroll
        for (int zz = 0; zz < NZ; ++zz) {
            lw[zz] = Ls[bn + zz * 16384] * fexp2(m[zz] - M);
            wsum += lw[zz];
        }
        const float inv = 1.0f / wsum;

        const size_t base = (size_t)bn * CDIM + c16;
        float acc[8] = {0.f, 0.f, 0.f, 0.f, 0.f, 0.f, 0.f, 0.f};
        #pragma unroll
        for (int zz = 0; zz < NZ; ++zz) {
            uint4 a = *(const uint4*)&Op[zz * PER + base];
            const unsigned short* p = (const unsigned short*)&a;
            #pragma unroll
            for (int j = 0; j < 8; ++j) acc[j] += lw[zz] * h2f(p[j]);
        }
        unsigned short mv[8];
        #pragma unroll
        for (int j = 0; j < 8; ++j) mv[j] = f2h(acc[j] * inv);
        *(uint4*)&As[row][c16] = *(const uint4*)mv;
    }
    {
        int o = t >> 2, ch = (t & 3) * 32;
        #pragma unroll
        for (int i = 0; i < 8; ++i) {
            float4 f4 = *(const float4*)&Wo[(size_t)(zo + o) * CDIM + ch + i * 4];
            ushort4 u = { f2h(f4.x), f2h(f4.y), f2h(f4.z), f2h(f4.w) };
            *(ushort4*)&Ws[o][ch + i * 4] = u;
        }
    }
    __syncthreads();

    f16x8 bA[4];
    #pragma unroll
    for (int f = 0; f < 4; ++f)
        bA[f] = *(const f16x8*)&As[w * 16 + l15][f * 32 + quad * 8];

    #pragma unroll
    for (int ot = 0; ot < 4; ++ot) {
        floatx4 acc = (floatx4){0.f, 0.f, 0.f, 0.f};
        #pragma unroll
        for (int f = 0; f < 4; ++f) {
            f16x8 aW = *(const f16x8*)&Ws[ot * 16 + l15][f * 32 + quad * 8];
            acc = mfma16(aW, bA[f], acc);
        }
        const int ob = zo + ot * 16 + quad * 4;
        #pragma unroll
        for (int r = 0; r < 4; ++r) {
            size_t idx = ((size_t)b * CDIM + ob + r) * NTOT + n0 + w * 16 + l15;
            out[idx] = acc[r] + bo[ob + r] + x[idx];
        }
    }
}

// ---------------------------------------------------------------------------
extern "C" void kernel_launch(void* const* d_in, const int* in_sizes, int n_in,
                              void* d_out, int out_size, void* d_ws, size_t ws_size,
                              hipStream_t stream)
{
    const float* x  = (const float*)d_in[0];
    const float* Wq = (const float*)d_in[1];
    const float* bq = (const float*)d_in[2];
    const float* Wk = (const float*)d_in[3];
    const float* bk = (const float*)d_in[4];
    const float* Wv = (const float*)d_in[5];
    const float* bv = (const float*)d_in[6];
    const float* Wo = (const float*)d_in[7];
    const float* bo = (const float*)d_in[8];
    float* out = (float*)d_out;

    const size_t PER = (size_t)4 * CDIM * NTOT;   // 2,097,152 elements
    unsigned short* q_ws  = (unsigned short*)d_ws;
    unsigned short* k_ws  = q_ws + PER;
    unsigned short* v_ws  = k_ws + PER;
    unsigned short* op_ws = v_ws + PER;           // fp16 [8][b][n][c] partials (32 MB)
    float*          ms_ws = (float*)(op_ws + (size_t)NZ * PER);   // [8][b*n]
    float*          ls_ws = ms_ws + (size_t)NZ * 16384;

    qkv_proj_kernel<<<dim3(64, 4, 2), dim3(256), 0, stream>>>(
        x, Wq, Wk, Wv, bq, bk, bv, q_ws, k_ws, v_ws);
    attn_kernel<<<dim3(512), dim3(512), 0, stream>>>(
        q_ws, k_ws, v_ws, op_ws, ms_ws, ls_ws);
    out_proj_kernel<<<dim3(64, 4, 2), dim3(256), 0, stream>>>(
        op_ws, ms_ws, ls_ws, Wo, bo, x, out);
}

// Round 15
// 137.883 us; speedup vs baseline: 1.1163x; 1.1163x over previous
//
#include <hip/hip_runtime.h>
#include <math.h>
#include <stdint.h>

#define CDIM 128
#define NTOT 4096
#define LOG2E 1.44269504f

typedef _Float16 f16x8 __attribute__((ext_vector_type(8)));  // 8 fp16 (4 VGPRs)
typedef float floatx4 __attribute__((ext_vector_type(4)));   // MFMA accumulator

static __device__ __forceinline__ floatx4 mfma16(f16x8 a, f16x8 b, floatx4 c) {
    return __builtin_amdgcn_mfma_f32_16x16x32_f16(a, b, c, 0, 0, 0);
}
static __device__ __forceinline__ unsigned short f2h(float f) {
    _Float16 h = (_Float16)f;
    return __builtin_bit_cast(unsigned short, h);
}
static __device__ __forceinline__ float h2f(unsigned short u) {
    return (float)__builtin_bit_cast(_Float16, u);
}
// raw v_exp_f32 (exp2). exp2f() libm adds denormal fixup VALU (R9 regression).
static __device__ __forceinline__ float fexp2(float x) {
#if __has_builtin(__builtin_amdgcn_exp2f)
    return __builtin_amdgcn_exp2f(x);
#else
    return exp2f(x);
#endif
}

// XOR-swizzled LDS addressing, rows of 128 ush (16 chunks of 16 B):
// chunk cc stored at linear slot cc ^ (row & 15).
#define SWZ(row, cc) ((((row) << 7)) + ((((cc) ^ ((row) & 15))) << 3))
// rows of 64 ush (8 chunks of 16 B): chunk cc at slot cc ^ (row & 7).
#define SWZ8(row, cc) ((((row) << 6)) + ((((cc) ^ ((row) & 7))) << 3))

// async global->LDS, 16 B per lane. LDS dest = wave-uniform base + lane*16
// (linear); swizzle realized by inverse-permuting the per-lane GLOBAL source.
static __device__ __forceinline__ void gload_lds16(const void* g, void* l) {
    __builtin_amdgcn_global_load_lds(
        (const __attribute__((address_space(1))) void*)g,
        (__attribute__((address_space(3))) void*)l, 16, 0, 0);
}

// ---------------------------------------------------------------------------
// Fused q/k/v projection (R7-best single-phase staging).
// q output scaled by LOG2E in f32 (exact) for base-2 softmax.
// x: [4][128][4096] fp32. Outputs fp16: qo, ko: [b][n][c]; vo: [b][c][n].
// grid (64 n-tiles, 4 batches, 2 o-halves), 256 threads / 4 waves.
// ---------------------------------------------------------------------------
__global__ __launch_bounds__(256) void qkv_proj_kernel(
    const float* __restrict__ x,
    const float* __restrict__ Wq, const float* __restrict__ Wk,
    const float* __restrict__ Wv,
    const float* __restrict__ bq, const float* __restrict__ bk,
    const float* __restrict__ bv,
    unsigned short* __restrict__ qo, unsigned short* __restrict__ ko,
    unsigned short* __restrict__ vo)
{
    __shared__ __align__(16) unsigned short Xs[64][136];      // [n][c] fp16
    __shared__ __align__(16) unsigned short Ws[3][64][136];   // [s][o-half][c] fp16

    const int t = threadIdx.x, b = blockIdx.y, n0 = blockIdx.x * 64;
    const int zo = blockIdx.z * 64;
    const int w = t >> 6, quad = (t >> 4) & 3, l15 = t & 15;

    // stage x tile with transpose-on-store: thread covers 4n x 8c
    {
        const int n = (t & 15) * 4;
        const int c = (t >> 4) * 8;
        float4 xr[8];
        #pragma unroll
        for (int j = 0; j < 8; ++j)
            xr[j] = *(const float4*)&x[((size_t)b * CDIM + c + j) * NTOT + n0 + n];
        #pragma unroll
        for (int k = 0; k < 4; ++k) {
            ushort4 ulo, uhi;
            ulo.x = f2h(((const float*)&xr[0])[k]);
            ulo.y = f2h(((const float*)&xr[1])[k]);
            ulo.z = f2h(((const float*)&xr[2])[k]);
            ulo.w = f2h(((const float*)&xr[3])[k]);
            uhi.x = f2h(((const float*)&xr[4])[k]);
            uhi.y = f2h(((const float*)&xr[5])[k]);
            uhi.z = f2h(((const float*)&xr[6])[k]);
            uhi.w = f2h(((const float*)&xr[7])[k]);
            *(ushort4*)&Xs[n + k][c]     = ulo;
            *(ushort4*)&Xs[n + k][c + 4] = uhi;
        }
    }
    // stage all three W o-halves (f32 -> f16): thread covers 1 o-row x 32c per s
    {
        const int o = t >> 2, ch = (t & 3) * 32;
        #pragma unroll
        for (int s = 0; s < 3; ++s) {
            const float* W = (s == 0) ? Wq : (s == 1) ? Wk : Wv;
            #pragma unroll
            for (int i = 0; i < 8; ++i) {
                float4 f4 = *(const float4*)&W[(size_t)(zo + o) * CDIM + ch + i * 4];
                ushort4 u = { f2h(f4.x), f2h(f4.y), f2h(f4.z), f2h(f4.w) };
                *(ushort4*)&Ws[s][o][ch + i * 4] = u;
            }
        }
    }
    __syncthreads();   // the ONLY barrier

    f16x8 xf[4];
    #pragma unroll
    for (int f = 0; f < 4; ++f)
        xf[f] = *(const f16x8*)&Xs[w * 16 + l15][f * 32 + quad * 8];

    // q, k: C[o][n], A = W, B = X. q gets the LOG2E scale (f32, exact).
    #pragma unroll
    for (int s = 0; s < 2; ++s) {
        const float* bias = s ? bk : bq;
        unsigned short* dst = s ? ko : qo;
        const float sc = (s == 0) ? LOG2E : 1.0f;
        #pragma unroll
        for (int ot = 0; ot < 4; ++ot) {
            floatx4 acc = (floatx4){0.f, 0.f, 0.f, 0.f};
            #pragma unroll
            for (int f = 0; f < 4; ++f) {
                f16x8 aW = *(const f16x8*)&Ws[s][ot * 16 + l15][f * 32 + quad * 8];
                acc = mfma16(aW, xf[f], acc);
            }
            const int ob = zo + ot * 16 + quad * 4;
            ushort4 u;
            u.x = f2h((acc[0] + bias[ob + 0]) * sc);
            u.y = f2h((acc[1] + bias[ob + 1]) * sc);
            u.z = f2h((acc[2] + bias[ob + 2]) * sc);
            u.w = f2h((acc[3] + bias[ob + 3]) * sc);
            *(ushort4*)&dst[((size_t)b * NTOT + n0 + w * 16 + l15) * CDIM + ob] = u;
        }
    }
    // v: C'[n][o], A = X, B = W
    #pragma unroll
    for (int ot = 0; ot < 4; ++ot) {
        floatx4 acc = (floatx4){0.f, 0.f, 0.f, 0.f};
        #pragma unroll
        for (int f = 0; f < 4; ++f) {
            f16x8 bW = *(const f16x8*)&Ws[2][ot * 16 + l15][f * 32 + quad * 8];
            acc = mfma16(xf[f], bW, acc);
        }
        const int o = zo + ot * 16 + l15;
        const float bv_ = bv[o];
        ushort4 u;
        u.x = f2h(acc[0] + bv_); u.y = f2h(acc[1] + bv_);
        u.z = f2h(acc[2] + bv_); u.w = f2h(acc[3] + bv_);
        *(ushort4*)&vo[((size_t)b * CDIM + o) * NTOT + n0 + w * 16 + quad * 4] = u;
    }
}

// ---------------------------------------------------------------------------
// Flash attention v10 (R13, measured best: 49.8 us): ONE GANG, ONE BARRIER,
// ZERO REDUNDANT STAGING. BQ=256, 8 waves (512 thr), 1 block/CU (LDS 112 KB).
// Per-wave schedule: pipelined softmax (QK[i] + PV[i-1] on the MFMA pipe
// while softmax[i] runs on VALU), K dbuf + V TRIPLE-buffer (barrier B
// eliminated: V[i+1] overwrites V[i-2]'s buffer whose readers finished at
// iter i-1), P in wave-private LDS rows. vmcnt ledger: steady 6 outstanding
// -> vmcnt(2) covers K[i]+V[i-1]. grid (256) flat w/ bijective XCD swizzle.
// Ms stats in log2 domain; base-2 softmax via raw v_exp_f32.
// ---------------------------------------------------------------------------
__global__ __launch_bounds__(512) void attn_kernel(
    const unsigned short* __restrict__ qg,
    const unsigned short* __restrict__ kg,
    const unsigned short* __restrict__ vg,
    unsigned short* __restrict__ Op,
    float* __restrict__ Ms, float* __restrict__ Ls)
{
    __shared__ __align__(16) unsigned short Kb[2][64 * 128];   // 16 KB each
    __shared__ __align__(16) unsigned short Vb[3][128 * 64];   // 16 KB each
    __shared__ __align__(16) unsigned short Ps[256 * 64];      // 32 KB wave-priv rows

    const int t = threadIdx.x;                        // 0..511
    const int w = t >> 6, quad = (t >> 4) & 3, l15 = t & 15;

    const int bid = blockIdx.x;                       // 256
    const int swz = ((bid & 7) << 5) | (bid >> 3);    // bijective, 32/XCD chunks
    const int gidx = swz >> 4;            // 0..15 = (b,z) group
    const int b = gidx & 3;
    const int z = gidx >> 2;              // 0..3
    const int i0 = (swz & 15) * 256;
    const int jbase = z * 1024;
    const size_t vbase = (size_t)b * CDIM * NTOT;

    // Q B-fragments direct from global (already LOG2E-scaled by qkv)
    f16x8 bQ[2][4];
    #pragma unroll
    for (int nt = 0; nt < 2; ++nt) {
        const size_t qrow = ((size_t)b * NTOT + i0 + w * 32 + nt * 16 + l15) * CDIM;
        #pragma unroll
        for (int f = 0; f < 4; ++f)
            bQ[nt][f] = *(const f16x8*)&qg[qrow + f * 32 + quad * 8];
    }

    // K tile [64 j][128 c] = 1024 chunks -> 2 per thread (512 thr).
    auto stageK = [&](unsigned short* Kd, int j0) {
        const size_t kbase = ((size_t)b * NTOT + j0) * CDIM;
        #pragma unroll
        for (int r = 0; r < 2; ++r) {
            const int flat = r * 512 + t;
            const int ldsoff = (r * 512 + (t & ~63)) * 8;  // wave-uniform, ush
            const int krow = flat >> 4, kcc = flat & 15;
            gload_lds16(&kg[kbase + (size_t)krow * CDIM + ((kcc ^ (krow & 15)) << 3)],
                        &Kd[ldsoff]);
        }
    };
    // V tile [128 d][64 j] = 1024 chunks -> 2 per thread.
    auto stageV = [&](unsigned short* Vd, int j0) {
        const size_t vrow0 = vbase + j0;
        #pragma unroll
        for (int r = 0; r < 2; ++r) {
            const int flat = r * 512 + t;
            const int ldsoff = (r * 512 + (t & ~63)) * 8;
            const int vrow = flat >> 3, vcc = flat & 7;
            gload_lds16(&vg[vrow0 + (size_t)vrow * NTOT + ((vcc ^ (vrow & 7)) << 3)],
                        &Vd[ldsoff]);
        }
    };

    floatx4 accO[2][8];   // [nt][dt]
    #pragma unroll
    for (int nt = 0; nt < 2; ++nt)
        #pragma unroll
        for (int dt = 0; dt < 8; ++dt) accO[nt][dt] = (floatx4){0.f, 0.f, 0.f, 0.f};
    float m_run[2] = {-INFINITY, -INFINITY};   // log2 domain
    float l_part[2] = {0.f, 0.f};

    floatx4 accT[2][4];
    uint2 pu[2][4];
    f16x8 bP[2][2];

    auto QK = [&](const unsigned short* Kd) {
        #pragma unroll
        for (int nt = 0; nt < 2; ++nt)
            #pragma unroll
            for (int jt = 0; jt < 4; ++jt) accT[nt][jt] = (floatx4){0.f, 0.f, 0.f, 0.f};
        __builtin_amdgcn_s_setprio(1);
        #pragma unroll
        for (int jt = 0; jt < 4; ++jt)
            #pragma unroll
            for (int f = 0; f < 4; ++f) {
                f16x8 aK = *(const f16x8*)&Kd[SWZ(jt * 16 + l15, f * 4 + quad)];
                accT[0][jt] = mfma16(aK, bQ[0][f], accT[0][jt]);
                accT[1][jt] = mfma16(aK, bQ[1][f], accT[1][jt]);
            }
        __builtin_amdgcn_s_setprio(0);
    };
    auto RB = [&]() {   // read P[i-1] fragments (own rows) early
        #pragma unroll
        for (int nt = 0; nt < 2; ++nt) {
            const int prow = w * 32 + nt * 16 + l15;
            #pragma unroll
            for (int kb = 0; kb < 2; ++kb)
                bP[nt][kb] = *(const f16x8*)&Ps[SWZ8(prow, kb * 4 + quad)];
        }
    };
    auto PV = [&](const unsigned short* Vd) {
        __builtin_amdgcn_s_setprio(1);
        #pragma unroll
        for (int dt = 0; dt < 8; ++dt)
            #pragma unroll
            for (int kb = 0; kb < 2; ++kb) {
                f16x8 aV = *(const f16x8*)&Vd[SWZ8(dt * 16 + l15, kb * 4 + quad)];
                accO[0][dt] = mfma16(aV, bP[0][kb], accO[0][dt]);
                accO[1][dt] = mfma16(aV, bP[1][kb], accO[1][dt]);
            }
        __builtin_amdgcn_s_setprio(0);
    };
    auto SM = [&]() {   // base-2 online softmax, defer-max (THR = 8*log2e)
        #pragma unroll
        for (int nt = 0; nt < 2; ++nt) {
            float tm = accT[nt][0][0];
            #pragma unroll
            for (int jt = 0; jt < 4; ++jt)
                #pragma unroll
                for (int r = 0; r < 4; ++r) tm = fmaxf(tm, accT[nt][jt][r]);
            tm = fmaxf(tm, __shfl_xor(tm, 16));
            tm = fmaxf(tm, __shfl_xor(tm, 32));
            if (__ballot(tm > m_run[nt] + 11.5416f)) {
                const float m_new = fmaxf(m_run[nt], tm);
                const float alpha = fexp2(m_run[nt] - m_new);   // 0 on first tile
                m_run[nt] = m_new;
                l_part[nt] *= alpha;
                #pragma unroll
                for (int dt = 0; dt < 8; ++dt) {
                    accO[nt][dt][0] *= alpha; accO[nt][dt][1] *= alpha;
                    accO[nt][dt][2] *= alpha; accO[nt][dt][3] *= alpha;
                }
            }
            const float mcur = m_run[nt];
            float ps = 0.f;
            #pragma unroll
            for (int jt = 0; jt < 4; ++jt) {
                float p0 = fexp2(accT[nt][jt][0] - mcur);
                float p1 = fexp2(accT[nt][jt][1] - mcur);
                float p2 = fexp2(accT[nt][jt][2] - mcur);
                float p3 = fexp2(accT[nt][jt][3] - mcur);
                ps += (p0 + p1) + (p2 + p3);
                pu[nt][jt].x = __builtin_bit_cast(unsigned int,
                                   __builtin_amdgcn_cvt_pkrtz(p0, p1));
                pu[nt][jt].y = __builtin_bit_cast(unsigned int,
                                   __builtin_amdgcn_cvt_pkrtz(p2, p3));
            }
            l_part[nt] += ps;
        }
    };
    auto WP = [&]() {   // write P[i] to own rows
        #pragma unroll
        for (int nt = 0; nt < 2; ++nt) {
            const int prow = w * 32 + nt * 16 + l15;
            #pragma unroll
            for (int jt = 0; jt < 4; ++jt)
                *(uint2*)&Ps[SWZ8(prow, 2 * jt + (quad >> 1)) + (quad & 1) * 4] =
                    pu[nt][jt];
        }
    };

    stageK(Kb[0], jbase);
    stageV(Vb[0], jbase);
    unsigned short *Kc = Kb[0], *Kn = Kb[1];
    unsigned short *Vprev = Vb[0], *Vcur = Vb[1], *Vnext = Vb[2];

    // ---- iter 0 (peeled): no PV ----
    asm volatile("s_waitcnt vmcnt(0) lgkmcnt(0)" ::: "memory");
    __builtin_amdgcn_s_barrier();
    stageK(Kn, jbase + 64);
    stageV(Vcur, jbase + 64);     // V[1] -> Vb[1]
    QK(Kc);
    SM();
    WP();
    { unsigned short* tp = Kc; Kc = Kn; Kn = tp; }
    // now: Vprev = V[0], Vcur = V[1] (in flight), Vnext = free

    // ---- iters 1..14: ONE barrier per iter ----
    for (int it = 1; it <= 14; ++it) {
        // (A) own K[it] + V[it-1] landed (vmcnt(2): V[it] may still fly) +
        // own LDS ops done; barrier extends to all waves -> V[it-2]'s buffer
        // (Vnext) is dead everywhere, K[it] / V[it-1] tiles complete.
        asm volatile("s_waitcnt vmcnt(2) lgkmcnt(0)" ::: "memory");
        __builtin_amdgcn_s_barrier();
        RB();                                   // P[it-1] (own rows)
        stageK(Kn, jbase + (it + 1) * 64);      // K[it+1]
        stageV(Vnext, jbase + (it + 1) * 64);   // V[it+1] into V[it-2]'s buffer
        QK(Kc);                                 // MFMA: K[it] x Q
        PV(Vprev);                              // MFMA: V[it-1] x P[it-1] (overlaps SM)
        SM();                                   // VALU: softmax[it]
        WP();                                   // P[it] (own rows)
        { unsigned short* tp = Kc; Kc = Kn; Kn = tp; }
        { unsigned short* tv = Vprev; Vprev = Vcur; Vcur = Vnext; Vnext = tv; }
    }

    // ---- iter 15 (peeled): no staging ----
    asm volatile("s_waitcnt vmcnt(2) lgkmcnt(0)" ::: "memory");
    __builtin_amdgcn_s_barrier();
    RB();
    QK(Kc);
    PV(Vprev);                                  // V[14]
    SM();
    WP();
    Vprev = Vcur;                               // V[15]
    // epilogue: all waves' V[15] staging landed + WP visible
    asm volatile("s_waitcnt vmcnt(0) lgkmcnt(0)" ::: "memory");
    __builtin_amdgcn_s_barrier();
    RB();
    PV(Vprev);

    // final l over quads; store normalized partials + stats (Ms in log2 domain)
    #pragma unroll
    for (int nt = 0; nt < 2; ++nt) {
        float lf = l_part[nt];
        lf += __shfl_xor(lf, 16);
        lf += __shfl_xor(lf, 32);
        const float inv = 1.0f / lf;
        const size_t orow =
            (((size_t)z * 4 + b) * NTOT + i0 + w * 32 + nt * 16 + l15) * CDIM;
        #pragma unroll
        for (int dt = 0; dt < 8; ++dt) {
            ushort4 u;
            u.x = f2h(accO[nt][dt][0] * inv); u.y = f2h(accO[nt][dt][1] * inv);
            u.z = f2h(accO[nt][dt][2] * inv); u.w = f2h(accO[nt][dt][3] * inv);
            *(ushort4*)&Op[orow + dt * 16 + quad * 4] = u;
        }
        if (quad == 0) {
            const int idx = (z * 4 + b) * NTOT + i0 + w * 32 + nt * 16 + l15;
            Ms[idx] = m_run[nt];
            Ls[idx] = lf;
        }
    }
}

// ---------------------------------------------------------------------------
// Output projection + residual with FUSED split-K(4) combine (base-2 merge;
// R13-identical).
// ---------------------------------------------------------------------------
__global__ __launch_bounds__(256) void out_proj_kernel(
    const unsigned short* __restrict__ Op,
    const float* __restrict__ Ms, const float* __restrict__ Ls,
    const float* __restrict__ Wo, const float* __restrict__ bo,
    const float* __restrict__ x, float* __restrict__ out)
{
    __shared__ __align__(16) unsigned short As[64][136];  // [n][c] merged
    __shared__ __align__(16) unsigned short Ws[64][136];  // [o-half][c]

    const int t = threadIdx.x, b = blockIdx.y, n0 = blockIdx.x * 64;
    const int zo = blockIdx.z * 64;
    const int w = t >> 6, quad = (t >> 4) & 3, l15 = t & 15;

    const size_t PER = (size_t)NTOT * 4 * CDIM;   // elements per key-quarter

    #pragma unroll
    for (int r = 0; r < 4; ++r) {   // stage merged ao tile
        int flat = r * 256 + t;
        int row = flat >> 4, c16 = (flat & 15) * 8;
        const int bn = b * NTOT + n0 + row;
        float m0 = Ms[bn], m1 = Ms[bn + 16384], m2 = Ms[bn + 32768], m3 = Ms[bn + 49152];
        float M = fmaxf(fmaxf(m0, m1), fmaxf(m2, m3));
        float w0 = Ls[bn]         * fexp2(m0 - M);
        float w1 = Ls[bn + 16384] * fexp2(m1 - M);
        float w2 = Ls[bn + 32768] * fexp2(m2 - M);
        float w3 = Ls[bn + 49152] * fexp2(m3 - M);
        const float inv = 1.0f / (w0 + w1 + w2 + w3);
        w0 *= inv; w1 *= inv; w2 *= inv; w3 *= inv;

        const size_t base = (size_t)bn * CDIM + c16;
        uint4 a0 = *(const uint4*)&Op[base];
        uint4 a1 = *(const uint4*)&Op[PER + base];
        uint4 a2 = *(const uint4*)&Op[2 * PER + base];
        uint4 a3 = *(const uint4*)&Op[3 * PER + base];
        const unsigned short* p0 = (const unsigned short*)&a0;
        const unsigned short* p1 = (const unsigned short*)&a1;
        const unsigned short* p2 = (const unsigned short*)&a2;
        const unsigned short* p3 = (const unsigned short*)&a3;
        unsigned short mv[8];
        #pragma unroll
        for (int j = 0; j < 8; ++j)
            mv[j] = f2h(w0 * h2f(p0[j]) + w1 * h2f(p1[j]) +
                        w2 * h2f(p2[j]) + w3 * h2f(p3[j]));
        *(uint4*)&As[row][c16] = *(const uint4*)mv;
    }
    {
        int o = t >> 2, ch = (t & 3) * 32;
        #pragma unroll
        for (int i = 0; i < 8; ++i) {
            float4 f4 = *(const float4*)&Wo[(size_t)(zo + o) * CDIM + ch + i * 4];
            ushort4 u = { f2h(f4.x), f2h(f4.y), f2h(f4.z), f2h(f4.w) };
            *(ushort4*)&Ws[o][ch + i * 4] = u;
        }
    }
    __syncthreads();

    f16x8 bA[4];
    #pragma unroll
    for (int f = 0; f < 4; ++f)
        bA[f] = *(const f16x8*)&As[w * 16 + l15][f * 32 + quad * 8];

    #pragma unroll
    for (int ot = 0; ot < 4; ++ot) {
        floatx4 acc = (floatx4){0.f, 0.f, 0.f, 0.f};
        #pragma unroll
        for (int f = 0; f < 4; ++f) {
            f16x8 aW = *(const f16x8*)&Ws[ot * 16 + l15][f * 32 + quad * 8];
            acc = mfma16(aW, bA[f], acc);
        }
        const int ob = zo + ot * 16 + quad * 4;
        #pragma unroll
        for (int r = 0; r < 4; ++r) {
            size_t idx = ((size_t)b * CDIM + ob + r) * NTOT + n0 + w * 16 + l15;
            out[idx] = acc[r] + bo[ob + r] + x[idx];
        }
    }
}

// ---------------------------------------------------------------------------
extern "C" void kernel_launch(void* const* d_in, const int* in_sizes, int n_in,
                              void* d_out, int out_size, void* d_ws, size_t ws_size,
                              hipStream_t stream)
{
    const float* x  = (const float*)d_in[0];
    const float* Wq = (const float*)d_in[1];
    const float* bq = (const float*)d_in[2];
    const float* Wk = (const float*)d_in[3];
    const float* bk = (const float*)d_in[4];
    const float* Wv = (const float*)d_in[5];
    const float* bv = (const float*)d_in[6];
    const float* Wo = (const float*)d_in[7];
    const float* bo = (const float*)d_in[8];
    float* out = (float*)d_out;

    const size_t PER = (size_t)4 * CDIM * NTOT;   // 2,097,152 elements
    unsigned short* q_ws  = (unsigned short*)d_ws;
    unsigned short* k_ws  = q_ws + PER;
    unsigned short* v_ws  = k_ws + PER;
    unsigned short* op_ws = v_ws + PER;           // fp16 [4][b][n][c] partials
    float*          ms_ws = (float*)(op_ws + 4 * PER);   // [4][b*n]
    float*          ls_ws = ms_ws + 4 * 16384;

    qkv_proj_kernel<<<dim3(64, 4, 2), dim3(256), 0, stream>>>(
        x, Wq, Wk, Wv, bq, bk, bv, q_ws, k_ws, v_ws);
    attn_kernel<<<dim3(256), dim3(512), 0, stream>>>(
        q_ws, k_ws, v_ws, op_ws, ms_ws, ls_ws);
    out_proj_kernel<<<dim3(64, 4, 2), dim3(256), 0, stream>>>(
        op_ws, ms_ws, ls_ws, Wo, bo, x, out);
}

// Round 16
// 136.348 us; speedup vs baseline: 1.1288x; 1.0113x over previous
//
#include <hip/hip_runtime.h>
#include <math.h>
#include <stdint.h>

#define CDIM 128
#define NTOT 4096
#define LOG2E 1.44269504f

typedef _Float16 f16x8 __attribute__((ext_vector_type(8)));  // 8 fp16 (4 VGPRs)
typedef float floatx4 __attribute__((ext_vector_type(4)));   // MFMA accumulator

static __device__ __forceinline__ floatx4 mfma16(f16x8 a, f16x8 b, floatx4 c) {
    return __builtin_amdgcn_mfma_f32_16x16x32_f16(a, b, c, 0, 0, 0);
}
static __device__ __forceinline__ unsigned short f2h(float f) {
    _Float16 h = (_Float16)f;
    return __builtin_bit_cast(unsigned short, h);
}
static __device__ __forceinline__ float h2f(unsigned short u) {
    return (float)__builtin_bit_cast(_Float16, u);
}
// raw v_exp_f32 (exp2). exp2f() libm adds denormal fixup VALU (R9 regression).
static __device__ __forceinline__ float fexp2(float x) {
#if __has_builtin(__builtin_amdgcn_exp2f)
    return __builtin_amdgcn_exp2f(x);
#else
    return exp2f(x);
#endif
}

// XOR-swizzled LDS addressing, rows of 128 ush (16 chunks of 16 B):
// chunk cc stored at linear slot cc ^ (row & 15).
#define SWZ(row, cc) ((((row) << 7)) + ((((cc) ^ ((row) & 15))) << 3))
// rows of 64 ush (8 chunks of 16 B): chunk cc at slot cc ^ (row & 7).
#define SWZ8(row, cc) ((((row) << 6)) + ((((cc) ^ ((row) & 7))) << 3))

// async global->LDS, 16 B per lane. LDS dest = wave-uniform base + lane*16
// (linear); swizzle realized by inverse-permuting the per-lane GLOBAL source.
static __device__ __forceinline__ void gload_lds16(const void* g, void* l) {
    __builtin_amdgcn_global_load_lds(
        (const __attribute__((address_space(1))) void*)g,
        (__attribute__((address_space(3))) void*)l, 16, 0, 0);
}

// ---------------------------------------------------------------------------
// Fused q/k/v projection (R7-best single-phase staging; unchanged).
// q output scaled by LOG2E in f32 (exact) for base-2 softmax.
// x: [4][128][4096] fp32. Outputs fp16: qo, ko: [b][n][c]; vo: [b][c][n].
// grid (64 n-tiles, 4 batches, 2 o-halves), 256 threads / 4 waves.
// ---------------------------------------------------------------------------
__global__ __launch_bounds__(256) void qkv_proj_kernel(
    const float* __restrict__ x,
    const float* __restrict__ Wq, const float* __restrict__ Wk,
    const float* __restrict__ Wv,
    const float* __restrict__ bq, const float* __restrict__ bk,
    const float* __restrict__ bv,
    unsigned short* __restrict__ qo, unsigned short* __restrict__ ko,
    unsigned short* __restrict__ vo)
{
    __shared__ __align__(16) unsigned short Xs[64][136];      // [n][c] fp16
    __shared__ __align__(16) unsigned short Ws[3][64][136];   // [s][o-half][c] fp16

    const int t = threadIdx.x, b = blockIdx.y, n0 = blockIdx.x * 64;
    const int zo = blockIdx.z * 64;
    const int w = t >> 6, quad = (t >> 4) & 3, l15 = t & 15;

    // stage x tile with transpose-on-store: thread covers 4n x 8c
    {
        const int n = (t & 15) * 4;
        const int c = (t >> 4) * 8;
        float4 xr[8];
        #pragma unroll
        for (int j = 0; j < 8; ++j)
            xr[j] = *(const float4*)&x[((size_t)b * CDIM + c + j) * NTOT + n0 + n];
        #pragma unroll
        for (int k = 0; k < 4; ++k) {
            ushort4 ulo, uhi;
            ulo.x = f2h(((const float*)&xr[0])[k]);
            ulo.y = f2h(((const float*)&xr[1])[k]);
            ulo.z = f2h(((const float*)&xr[2])[k]);
            ulo.w = f2h(((const float*)&xr[3])[k]);
            uhi.x = f2h(((const float*)&xr[4])[k]);
            uhi.y = f2h(((const float*)&xr[5])[k]);
            uhi.z = f2h(((const float*)&xr[6])[k]);
            uhi.w = f2h(((const float*)&xr[7])[k]);
            *(ushort4*)&Xs[n + k][c]     = ulo;
            *(ushort4*)&Xs[n + k][c + 4] = uhi;
        }
    }
    // stage all three W o-halves (f32 -> f16): thread covers 1 o-row x 32c per s
    {
        const int o = t >> 2, ch = (t & 3) * 32;
        #pragma unroll
        for (int s = 0; s < 3; ++s) {
            const float* W = (s == 0) ? Wq : (s == 1) ? Wk : Wv;
            #pragma unroll
            for (int i = 0; i < 8; ++i) {
                float4 f4 = *(const float4*)&W[(size_t)(zo + o) * CDIM + ch + i * 4];
                ushort4 u = { f2h(f4.x), f2h(f4.y), f2h(f4.z), f2h(f4.w) };
                *(ushort4*)&Ws[s][o][ch + i * 4] = u;
            }
        }
    }
    __syncthreads();   // the ONLY barrier

    f16x8 xf[4];
    #pragma unroll
    for (int f = 0; f < 4; ++f)
        xf[f] = *(const f16x8*)&Xs[w * 16 + l15][f * 32 + quad * 8];

    // q, k: C[o][n], A = W, B = X. q gets the LOG2E scale (f32, exact).
    #pragma unroll
    for (int s = 0; s < 2; ++s) {
        const float* bias = s ? bk : bq;
        unsigned short* dst = s ? ko : qo;
        const float sc = (s == 0) ? LOG2E : 1.0f;
        #pragma unroll
        for (int ot = 0; ot < 4; ++ot) {
            floatx4 acc = (floatx4){0.f, 0.f, 0.f, 0.f};
            #pragma unroll
            for (int f = 0; f < 4; ++f) {
                f16x8 aW = *(const f16x8*)&Ws[s][ot * 16 + l15][f * 32 + quad * 8];
                acc = mfma16(aW, xf[f], acc);
            }
            const int ob = zo + ot * 16 + quad * 4;
            ushort4 u;
            u.x = f2h((acc[0] + bias[ob + 0]) * sc);
            u.y = f2h((acc[1] + bias[ob + 1]) * sc);
            u.z = f2h((acc[2] + bias[ob + 2]) * sc);
            u.w = f2h((acc[3] + bias[ob + 3]) * sc);
            *(ushort4*)&dst[((size_t)b * NTOT + n0 + w * 16 + l15) * CDIM + ob] = u;
        }
    }
    // v: C'[n][o], A = X, B = W
    #pragma unroll
    for (int ot = 0; ot < 4; ++ot) {
        floatx4 acc = (floatx4){0.f, 0.f, 0.f, 0.f};
        #pragma unroll
        for (int f = 0; f < 4; ++f) {
            f16x8 bW = *(const f16x8*)&Ws[2][ot * 16 + l15][f * 32 + quad * 8];
            acc = mfma16(xf[f], bW, acc);
        }
        const int o = zo + ot * 16 + l15;
        const float bv_ = bv[o];
        ushort4 u;
        u.x = f2h(acc[0] + bv_); u.y = f2h(acc[1] + bv_);
        u.z = f2h(acc[2] + bv_); u.w = f2h(acc[3] + bv_);
        *(ushort4*)&vo[((size_t)b * CDIM + o) * NTOT + n0 + w * 16 + quad * 4] = u;
    }
}

// ---------------------------------------------------------------------------
// Flash attention v12: R13 structure (ONE gang, ONE barrier, zero redundant
// staging, K dbuf + V triple, P in wave-private LDS rows) with PV(x)SM FUSED
// at dt granularity: per dt, 4 PV MFMAs -> rescale accO[.][dt] -> one
// branch-free exp/pack slice (nt,jt). In the single phase-locked gang,
// in-wave cross-pipe co-issue is the only MFMA/VALU overlap source; the
// interleave feeds both pipes from one wave. Defer-max dropped: alpha =
// 2^(m_old-m_new) is exactly 1 when no new max (numerics unchanged) and the
// rescale muls hide under the MFMA shadow. SMpre (max-reduce + alpha) runs
// right after QK. Everything else byte-identical to R13/R15.
// ---------------------------------------------------------------------------
__global__ __launch_bounds__(512) void attn_kernel(
    const unsigned short* __restrict__ qg,
    const unsigned short* __restrict__ kg,
    const unsigned short* __restrict__ vg,
    unsigned short* __restrict__ Op,
    float* __restrict__ Ms, float* __restrict__ Ls)
{
    __shared__ __align__(16) unsigned short Kb[2][64 * 128];   // 16 KB each
    __shared__ __align__(16) unsigned short Vb[3][128 * 64];   // 16 KB each
    __shared__ __align__(16) unsigned short Ps[256 * 64];      // 32 KB wave-priv rows

    const int t = threadIdx.x;                        // 0..511
    const int w = t >> 6, quad = (t >> 4) & 3, l15 = t & 15;

    const int bid = blockIdx.x;                       // 256
    const int swz = ((bid & 7) << 5) | (bid >> 3);    // bijective, 32/XCD chunks
    const int gidx = swz >> 4;            // 0..15 = (b,z) group
    const int b = gidx & 3;
    const int z = gidx >> 2;              // 0..3
    const int i0 = (swz & 15) * 256;
    const int jbase = z * 1024;
    const size_t vbase = (size_t)b * CDIM * NTOT;

    // Q B-fragments direct from global (already LOG2E-scaled by qkv)
    f16x8 bQ[2][4];
    #pragma unroll
    for (int nt = 0; nt < 2; ++nt) {
        const size_t qrow = ((size_t)b * NTOT + i0 + w * 32 + nt * 16 + l15) * CDIM;
        #pragma unroll
        for (int f = 0; f < 4; ++f)
            bQ[nt][f] = *(const f16x8*)&qg[qrow + f * 32 + quad * 8];
    }

    // K tile [64 j][128 c] = 1024 chunks -> 2 per thread (512 thr).
    auto stageK = [&](unsigned short* Kd, int j0) {
        const size_t kbase = ((size_t)b * NTOT + j0) * CDIM;
        #pragma unroll
        for (int r = 0; r < 2; ++r) {
            const int flat = r * 512 + t;
            const int ldsoff = (r * 512 + (t & ~63)) * 8;  // wave-uniform, ush
            const int krow = flat >> 4, kcc = flat & 15;
            gload_lds16(&kg[kbase + (size_t)krow * CDIM + ((kcc ^ (krow & 15)) << 3)],
                        &Kd[ldsoff]);
        }
    };
    // V tile [128 d][64 j] = 1024 chunks -> 2 per thread.
    auto stageV = [&](unsigned short* Vd, int j0) {
        const size_t vrow0 = vbase + j0;
        #pragma unroll
        for (int r = 0; r < 2; ++r) {
            const int flat = r * 512 + t;
            const int ldsoff = (r * 512 + (t & ~63)) * 8;
            const int vrow = flat >> 3, vcc = flat & 7;
            gload_lds16(&vg[vrow0 + (size_t)vrow * NTOT + ((vcc ^ (vrow & 7)) << 3)],
                        &Vd[ldsoff]);
        }
    };

    floatx4 accO[2][8];   // [nt][dt]
    #pragma unroll
    for (int nt = 0; nt < 2; ++nt)
        #pragma unroll
        for (int dt = 0; dt < 8; ++dt) accO[nt][dt] = (floatx4){0.f, 0.f, 0.f, 0.f};
    float m_run[2] = {-INFINITY, -INFINITY};   // log2 domain
    float l_part[2] = {0.f, 0.f};

    floatx4 accT[2][4];
    uint2 pu[2][4];
    f16x8 bP[2][2];
    float alpha[2], mcur[2], ps[2];

    auto QK = [&](const unsigned short* Kd) {
        #pragma unroll
        for (int nt = 0; nt < 2; ++nt)
            #pragma unroll
            for (int jt = 0; jt < 4; ++jt) accT[nt][jt] = (floatx4){0.f, 0.f, 0.f, 0.f};
        __builtin_amdgcn_s_setprio(1);
        #pragma unroll
        for (int jt = 0; jt < 4; ++jt)
            #pragma unroll
            for (int f = 0; f < 4; ++f) {
                f16x8 aK = *(const f16x8*)&Kd[SWZ(jt * 16 + l15, f * 4 + quad)];
                accT[0][jt] = mfma16(aK, bQ[0][f], accT[0][jt]);
                accT[1][jt] = mfma16(aK, bQ[1][f], accT[1][jt]);
            }
        __builtin_amdgcn_s_setprio(0);
    };
    auto RB = [&]() {   // read P[i-1] fragments (own rows) early
        #pragma unroll
        for (int nt = 0; nt < 2; ++nt) {
            const int prow = w * 32 + nt * 16 + l15;
            #pragma unroll
            for (int kb = 0; kb < 2; ++kb)
                bP[nt][kb] = *(const f16x8*)&Ps[SWZ8(prow, kb * 4 + quad)];
        }
    };
    // SMpre: per-lane max reduce + alpha (unconditional; =1 when no new max),
    // running-stat updates. Depends only on accT.
    auto SMpre = [&]() {
        ps[0] = 0.f; ps[1] = 0.f;
        #pragma unroll
        for (int nt = 0; nt < 2; ++nt) {
            float tm = accT[nt][0][0];
            #pragma unroll
            for (int jt = 0; jt < 4; ++jt)
                #pragma unroll
                for (int r = 0; r < 4; ++r) tm = fmaxf(tm, accT[nt][jt][r]);
            tm = fmaxf(tm, __shfl_xor(tm, 16));
            tm = fmaxf(tm, __shfl_xor(tm, 32));
            const float mnew = fmaxf(m_run[nt], tm);
            alpha[nt] = fexp2(m_run[nt] - mnew);   // 0 on first tile; 1 if no new max
            m_run[nt] = mnew;
            mcur[nt] = mnew;
            l_part[nt] *= alpha[nt];
        }
    };
    // one branch-free exp/pack slice: (snt, sjt)
    auto SLICE = [&](int snt, int sjt) {
        float p0 = fexp2(accT[snt][sjt][0] - mcur[snt]);
        float p1 = fexp2(accT[snt][sjt][1] - mcur[snt]);
        float p2 = fexp2(accT[snt][sjt][2] - mcur[snt]);
        float p3 = fexp2(accT[snt][sjt][3] - mcur[snt]);
        ps[snt] += (p0 + p1) + (p2 + p3);
        pu[snt][sjt].x = __builtin_bit_cast(unsigned int,
                             __builtin_amdgcn_cvt_pkrtz(p0, p1));
        pu[snt][sjt].y = __builtin_bit_cast(unsigned int,
                             __builtin_amdgcn_cvt_pkrtz(p2, p3));
    };
    // fused PV(x)SM: per dt -> 4 PV MFMAs, rescale accO[.][dt], one SLICE.
    // Rescale AFTER the adds (P[i-1] contribution is at m[i-1] scale and must
    // be rescaled to m[i] along with the running sum -- identical to R13's
    // PV-then-SM-rescale semantics, just at dt granularity).
    auto PVSM = [&](const unsigned short* Vd) {
        #pragma unroll
        for (int dt = 0; dt < 8; ++dt) {
            f16x8 aV0 = *(const f16x8*)&Vd[SWZ8(dt * 16 + l15, 0 * 4 + quad)];
            f16x8 aV1 = *(const f16x8*)&Vd[SWZ8(dt * 16 + l15, 1 * 4 + quad)];
            accO[0][dt] = mfma16(aV0, bP[0][0], accO[0][dt]);
            accO[1][dt] = mfma16(aV0, bP[1][0], accO[1][dt]);
            accO[0][dt] = mfma16(aV1, bP[0][1], accO[0][dt]);
            accO[1][dt] = mfma16(aV1, bP[1][1], accO[1][dt]);
            accO[0][dt][0] *= alpha[0]; accO[0][dt][1] *= alpha[0];
            accO[0][dt][2] *= alpha[0]; accO[0][dt][3] *= alpha[0];
            accO[1][dt][0] *= alpha[1]; accO[1][dt][1] *= alpha[1];
            accO[1][dt][2] *= alpha[1]; accO[1][dt][3] *= alpha[1];
            SLICE(dt >> 2, dt & 3);
        }
    };
    auto PVonly = [&](const unsigned short* Vd) {   // epilogue PV, no SM
        #pragma unroll
        for (int dt = 0; dt < 8; ++dt)
            #pragma unroll
            for (int kb = 0; kb < 2; ++kb) {
                f16x8 aV = *(const f16x8*)&Vd[SWZ8(dt * 16 + l15, kb * 4 + quad)];
                accO[0][dt] = mfma16(aV, bP[0][kb], accO[0][dt]);
                accO[1][dt] = mfma16(aV, bP[1][kb], accO[1][dt]);
            }
    };
    auto WP = [&]() {   // write P[i] to own rows
        #pragma unroll
        for (int nt = 0; nt < 2; ++nt) {
            const int prow = w * 32 + nt * 16 + l15;
            #pragma unroll
            for (int jt = 0; jt < 4; ++jt)
                *(uint2*)&Ps[SWZ8(prow, 2 * jt + (quad >> 1)) + (quad & 1) * 4] =
                    pu[nt][jt];
        }
    };

    stageK(Kb[0], jbase);
    stageV(Vb[0], jbase);
    unsigned short *Kc = Kb[0], *Kn = Kb[1];
    unsigned short *Vprev = Vb[0], *Vcur = Vb[1], *Vnext = Vb[2];

    // ---- iter 0 (peeled): no PV ----
    asm volatile("s_waitcnt vmcnt(0) lgkmcnt(0)" ::: "memory");
    __builtin_amdgcn_s_barrier();
    stageK(Kn, jbase + 64);
    stageV(Vcur, jbase + 64);     // V[1] -> Vb[1]
    QK(Kc);
    SMpre();
    #pragma unroll
    for (int s = 0; s < 8; ++s) SLICE(s >> 2, s & 3);
    l_part[0] += ps[0]; l_part[1] += ps[1];
    WP();
    { unsigned short* tp = Kc; Kc = Kn; Kn = tp; }
    // now: Vprev = V[0], Vcur = V[1] (in flight), Vnext = free

    // ---- iters 1..14: ONE barrier per iter ----
    for (int it = 1; it <= 14; ++it) {
        // (A) own K[it] + V[it-1] landed (vmcnt(2): V[it] may still fly) +
        // own LDS ops done; barrier extends to all waves -> V[it-2]'s buffer
        // (Vnext) is dead everywhere, K[it] / V[it-1] tiles complete.
        asm volatile("s_waitcnt vmcnt(2) lgkmcnt(0)" ::: "memory");
        __builtin_amdgcn_s_barrier();
        RB();                                   // P[it-1] (own rows)
        stageK(Kn, jbase + (it + 1) * 64);      // K[it+1]
        stageV(Vnext, jbase + (it + 1) * 64);   // V[it+1] into V[it-2]'s buffer
        QK(Kc);                                 // MFMA: K[it] x Q
        SMpre();                                // VALU: max/alpha (overlaps QK tail)
        PVSM(Vprev);                            // MFMA(PV) x VALU(exp/pack) co-issue
        l_part[0] += ps[0]; l_part[1] += ps[1];
        WP();                                   // P[it] (own rows)
        { unsigned short* tp = Kc; Kc = Kn; Kn = tp; }
        { unsigned short* tv = Vprev; Vprev = Vcur; Vcur = Vnext; Vnext = tv; }
    }

    // ---- iter 15 (peeled): no staging ----
    asm volatile("s_waitcnt vmcnt(2) lgkmcnt(0)" ::: "memory");
    __builtin_amdgcn_s_barrier();
    RB();
    QK(Kc);
    SMpre();
    PVSM(Vprev);                                // V[14]
    l_part[0] += ps[0]; l_part[1] += ps[1];
    WP();
    Vprev = Vcur;                               // V[15]
    // epilogue: all waves' V[15] staging landed + WP visible
    asm volatile("s_waitcnt vmcnt(0) lgkmcnt(0)" ::: "memory");
    __builtin_amdgcn_s_barrier();
    RB();
    PVonly(Vprev);

    // final l over quads; store normalized partials + stats (Ms in log2 domain)
    #pragma unroll
    for (int nt = 0; nt < 2; ++nt) {
        float lf = l_part[nt];
        lf += __shfl_xor(lf, 16);
        lf += __shfl_xor(lf, 32);
        const float inv = 1.0f / lf;
        const size_t orow =
            (((size_t)z * 4 + b) * NTOT + i0 + w * 32 + nt * 16 + l15) * CDIM;
        #pragma unroll
        for (int dt = 0; dt < 8; ++dt) {
            ushort4 u;
            u.x = f2h(accO[nt][dt][0] * inv); u.y = f2h(accO[nt][dt][1] * inv);
            u.z = f2h(accO[nt][dt][2] * inv); u.w = f2h(accO[nt][dt][3] * inv);
            *(ushort4*)&Op[orow + dt * 16 + quad * 4] = u;
        }
        if (quad == 0) {
            const int idx = (z * 4 + b) * NTOT + i0 + w * 32 + nt * 16 + l15;
            Ms[idx] = m_run[nt];
            Ls[idx] = lf;
        }
    }
}

// ---------------------------------------------------------------------------
// Output projection + residual with FUSED split-K(4) combine (base-2 merge;
// R13-identical).
// ---------------------------------------------------------------------------
__global__ __launch_bounds__(256) void out_proj_kernel(
    const unsigned short* __restrict__ Op,
    const float* __restrict__ Ms, const float* __restrict__ Ls,
    const float* __restrict__ Wo, const float* __restrict__ bo,
    const float* __restrict__ x, float* __restrict__ out)
{
    __shared__ __align__(16) unsigned short As[64][136];  // [n][c] merged
    __shared__ __align__(16) unsigned short Ws[64][136];  // [o-half][c]

    const int t = threadIdx.x, b = blockIdx.y, n0 = blockIdx.x * 64;
    const int zo = blockIdx.z * 64;
    const int w = t >> 6, quad = (t >> 4) & 3, l15 = t & 15;

    const size_t PER = (size_t)NTOT * 4 * CDIM;   // elements per key-quarter

    #pragma unroll
    for (int r = 0; r < 4; ++r) {   // stage merged ao tile
        int flat = r * 256 + t;
        int row = flat >> 4, c16 = (flat & 15) * 8;
        const int bn = b * NTOT + n0 + row;
        float m0 = Ms[bn], m1 = Ms[bn + 16384], m2 = Ms[bn + 32768], m3 = Ms[bn + 49152];
        float M = fmaxf(fmaxf(m0, m1), fmaxf(m2, m3));
        float w0 = Ls[bn]         * fexp2(m0 - M);
        float w1 = Ls[bn + 16384] * fexp2(m1 - M);
        float w2 = Ls[bn + 32768] * fexp2(m2 - M);
        float w3 = Ls[bn + 49152] * fexp2(m3 - M);
        const float inv = 1.0f / (w0 + w1 + w2 + w3);
        w0 *= inv; w1 *= inv; w2 *= inv; w3 *= inv;

        const size_t base = (size_t)bn * CDIM + c16;
        uint4 a0 = *(const uint4*)&Op[base];
        uint4 a1 = *(const uint4*)&Op[PER + base];
        uint4 a2 = *(const uint4*)&Op[2 * PER + base];
        uint4 a3 = *(const uint4*)&Op[3 * PER + base];
        const unsigned short* p0 = (const unsigned short*)&a0;
        const unsigned short* p1 = (const unsigned short*)&a1;
        const unsigned short* p2 = (const unsigned short*)&a2;
        const unsigned short* p3 = (const unsigned short*)&a3;
        unsigned short mv[8];
        #pragma unroll
        for (int j = 0; j < 8; ++j)
            mv[j] = f2h(w0 * h2f(p0[j]) + w1 * h2f(p1[j]) +
                        w2 * h2f(p2[j]) + w3 * h2f(p3[j]));
        *(uint4*)&As[row][c16] = *(const uint4*)mv;
    }
    {
        int o = t >> 2, ch = (t & 3) * 32;
        #pragma unroll
        for (int i = 0; i < 8; ++i) {
            float4 f4 = *(const float4*)&Wo[(size_t)(zo + o) * CDIM + ch + i * 4];
            ushort4 u = { f2h(f4.x), f2h(f4.y), f2h(f4.z), f2h(f4.w) };
            *(ushort4*)&Ws[o][ch + i * 4] = u;
        }
    }
    __syncthreads();

    f16x8 bA[4];
    #pragma unroll
    for (int f = 0; f < 4; ++f)
        bA[f] = *(const f16x8*)&As[w * 16 + l15][f * 32 + quad * 8];

    #pragma unroll
    for (int ot = 0; ot < 4; ++ot) {
        floatx4 acc = (floatx4){0.f, 0.f, 0.f, 0.f};
        #pragma unroll
        for (int f = 0; f < 4; ++f) {
            f16x8 aW = *(const f16x8*)&Ws[ot * 16 + l15][f * 32 + quad * 8];
            acc = mfma16(aW, bA[f], acc);
        }
        const int ob = zo + ot * 16 + quad * 4;
        #pragma unroll
        for (int r = 0; r < 4; ++r) {
            size_t idx = ((size_t)b * CDIM + ob + r) * NTOT + n0 + w * 16 + l15;
            out[idx] = acc[r] + bo[ob + r] + x[idx];
        }
    }
}

// ---------------------------------------------------------------------------
extern "C" void kernel_launch(void* const* d_in, const int* in_sizes, int n_in,
                              void* d_out, int out_size, void* d_ws, size_t ws_size,
                              hipStream_t stream)
{
    const float* x  = (const float*)d_in[0];
    const float* Wq = (const float*)d_in[1];
    const float* bq = (const float*)d_in[2];
    const float* Wk = (const float*)d_in[3];
    const float* bk = (const float*)d_in[4];
    const float* Wv = (const float*)d_in[5];
    const float* bv = (const float*)d_in[6];
    const float* Wo = (const float*)d_in[7];
    const float* bo = (const float*)d_in[8];
    float* out = (float*)d_out;

    const size_t PER = (size_t)4 * CDIM * NTOT;   // 2,097,152 elements
    unsigned short* q_ws  = (unsigned short*)d_ws;
    unsigned short* k_ws  = q_ws + PER;
    unsigned short* v_ws  = k_ws + PER;
    unsigned short* op_ws = v_ws + PER;           // fp16 [4][b][n][c] partials
    float*          ms_ws = (float*)(op_ws + 4 * PER);   // [4][b*n]
    float*          ls_ws = ms_ws + 4 * 16384;

    qkv_proj_kernel<<<dim3(64, 4, 2), dim3(256), 0, stream>>>(
        x, Wq, Wk, Wv, bq, bk, bv, q_ws, k_ws, v_ws);
    attn_kernel<<<dim3(256), dim3(512), 0, stream>>>(
        q_ws, k_ws, v_ws, op_ws, ms_ws, ls_ws);
    out_proj_kernel<<<dim3(64, 4, 2), dim3(256), 0, stream>>>(
        op_ws, ms_ws, ls_ws, Wo, bo, x, out);
}

// Round 17
// 134.034 us; speedup vs baseline: 1.1483x; 1.0173x over previous
//
#include <hip/hip_runtime.h>
#include <math.h>
#include <stdint.h>

#define CDIM 128
#define NTOT 4096
#define LOG2E 1.44269504f

typedef _Float16 f16x8 __attribute__((ext_vector_type(8)));  // 8 fp16 (4 VGPRs)
typedef float floatx4 __attribute__((ext_vector_type(4)));   // MFMA accumulator

static __device__ __forceinline__ floatx4 mfma16(f16x8 a, f16x8 b, floatx4 c) {
    return __builtin_amdgcn_mfma_f32_16x16x32_f16(a, b, c, 0, 0, 0);
}
static __device__ __forceinline__ unsigned short f2h(float f) {
    _Float16 h = (_Float16)f;
    return __builtin_bit_cast(unsigned short, h);
}
static __device__ __forceinline__ float h2f(unsigned short u) {
    return (float)__builtin_bit_cast(_Float16, u);
}
// raw v_exp_f32 (exp2). exp2f() libm adds denormal fixup VALU (R9 regression).
static __device__ __forceinline__ float fexp2(float x) {
#if __has_builtin(__builtin_amdgcn_exp2f)
    return __builtin_amdgcn_exp2f(x);
#else
    return exp2f(x);
#endif
}

// XOR-swizzled LDS addressing, rows of 128 ush (16 chunks of 16 B):
// chunk cc stored at linear slot cc ^ (row & 15).
#define SWZ(row, cc) ((((row) << 7)) + ((((cc) ^ ((row) & 15))) << 3))
// rows of 64 ush (8 chunks of 16 B): chunk cc at slot cc ^ (row & 7).
#define SWZ8(row, cc) ((((row) << 6)) + ((((cc) ^ ((row) & 7))) << 3))

// async global->LDS, 16 B per lane. LDS dest = wave-uniform base + lane*16
// (linear); swizzle realized by inverse-permuting the per-lane GLOBAL source.
static __device__ __forceinline__ void gload_lds16(const void* g, void* l) {
    __builtin_amdgcn_global_load_lds(
        (const __attribute__((address_space(1))) void*)g,
        (__attribute__((address_space(3))) void*)l, 16, 0, 0);
}

// ---------------------------------------------------------------------------
// Fused q/k/v projection (R7-best single-phase staging; unchanged).
// q output scaled by LOG2E in f32 (exact) for base-2 softmax.
// x: [4][128][4096] fp32. Outputs fp16: qo, ko: [b][n][c]; vo: [b][c][n].
// grid (64 n-tiles, 4 batches, 2 o-halves), 256 threads / 4 waves.
// ---------------------------------------------------------------------------
__global__ __launch_bounds__(256) void qkv_proj_kernel(
    const float* __restrict__ x,
    const float* __restrict__ Wq, const float* __restrict__ Wk,
    const float* __restrict__ Wv,
    const float* __restrict__ bq, const float* __restrict__ bk,
    const float* __restrict__ bv,
    unsigned short* __restrict__ qo, unsigned short* __restrict__ ko,
    unsigned short* __restrict__ vo)
{
    __shared__ __align__(16) unsigned short Xs[64][136];      // [n][c] fp16
    __shared__ __align__(16) unsigned short Ws[3][64][136];   // [s][o-half][c] fp16

    const int t = threadIdx.x, b = blockIdx.y, n0 = blockIdx.x * 64;
    const int zo = blockIdx.z * 64;
    const int w = t >> 6, quad = (t >> 4) & 3, l15 = t & 15;

    // stage x tile with transpose-on-store: thread covers 4n x 8c
    {
        const int n = (t & 15) * 4;
        const int c = (t >> 4) * 8;
        float4 xr[8];
        #pragma unroll
        for (int j = 0; j < 8; ++j)
            xr[j] = *(const float4*)&x[((size_t)b * CDIM + c + j) * NTOT + n0 + n];
        #pragma unroll
        for (int k = 0; k < 4; ++k) {
            ushort4 ulo, uhi;
            ulo.x = f2h(((const float*)&xr[0])[k]);
            ulo.y = f2h(((const float*)&xr[1])[k]);
            ulo.z = f2h(((const float*)&xr[2])[k]);
            ulo.w = f2h(((const float*)&xr[3])[k]);
            uhi.x = f2h(((const float*)&xr[4])[k]);
            uhi.y = f2h(((const float*)&xr[5])[k]);
            uhi.z = f2h(((const float*)&xr[6])[k]);
            uhi.w = f2h(((const float*)&xr[7])[k]);
            *(ushort4*)&Xs[n + k][c]     = ulo;
            *(ushort4*)&Xs[n + k][c + 4] = uhi;
        }
    }
    // stage all three W o-halves (f32 -> f16): thread covers 1 o-row x 32c per s
    {
        const int o = t >> 2, ch = (t & 3) * 32;
        #pragma unroll
        for (int s = 0; s < 3; ++s) {
            const float* W = (s == 0) ? Wq : (s == 1) ? Wk : Wv;
            #pragma unroll
            for (int i = 0; i < 8; ++i) {
                float4 f4 = *(const float4*)&W[(size_t)(zo + o) * CDIM + ch + i * 4];
                ushort4 u = { f2h(f4.x), f2h(f4.y), f2h(f4.z), f2h(f4.w) };
                *(ushort4*)&Ws[s][o][ch + i * 4] = u;
            }
        }
    }
    __syncthreads();   // the ONLY barrier

    f16x8 xf[4];
    #pragma unroll
    for (int f = 0; f < 4; ++f)
        xf[f] = *(const f16x8*)&Xs[w * 16 + l15][f * 32 + quad * 8];

    // q, k: C[o][n], A = W, B = X. q gets the LOG2E scale (f32, exact).
    #pragma unroll
    for (int s = 0; s < 2; ++s) {
        const float* bias = s ? bk : bq;
        unsigned short* dst = s ? ko : qo;
        const float sc = (s == 0) ? LOG2E : 1.0f;
        #pragma unroll
        for (int ot = 0; ot < 4; ++ot) {
            floatx4 acc = (floatx4){0.f, 0.f, 0.f, 0.f};
            #pragma unroll
            for (int f = 0; f < 4; ++f) {
                f16x8 aW = *(const f16x8*)&Ws[s][ot * 16 + l15][f * 32 + quad * 8];
                acc = mfma16(aW, xf[f], acc);
            }
            const int ob = zo + ot * 16 + quad * 4;
            ushort4 u;
            u.x = f2h((acc[0] + bias[ob + 0]) * sc);
            u.y = f2h((acc[1] + bias[ob + 1]) * sc);
            u.z = f2h((acc[2] + bias[ob + 2]) * sc);
            u.w = f2h((acc[3] + bias[ob + 3]) * sc);
            *(ushort4*)&dst[((size_t)b * NTOT + n0 + w * 16 + l15) * CDIM + ob] = u;
        }
    }
    // v: C'[n][o], A = X, B = W
    #pragma unroll
    for (int ot = 0; ot < 4; ++ot) {
        floatx4 acc = (floatx4){0.f, 0.f, 0.f, 0.f};
        #pragma unroll
        for (int f = 0; f < 4; ++f) {
            f16x8 bW = *(const f16x8*)&Ws[2][ot * 16 + l15][f * 32 + quad * 8];
            acc = mfma16(xf[f], bW, acc);
        }
        const int o = zo + ot * 16 + l15;
        const float bv_ = bv[o];
        ushort4 u;
        u.x = f2h(acc[0] + bv_); u.y = f2h(acc[1] + bv_);
        u.z = f2h(acc[2] + bv_); u.w = f2h(acc[3] + bv_);
        *(ushort4*)&vo[((size_t)b * CDIM + o) * NTOT + n0 + w * 16 + quad * 4] = u;
    }
}

// ---------------------------------------------------------------------------
// Flash attention v13: R16 (fused PV(x)SM at dt granularity) with the P
// ds_writes FOLDED INTO THE SLICES: each exp/pack slice immediately writes
// its pu pair, so all 8 ds_write_b64 land under the in-flight PV MFMAs
// instead of forming a serial WP block after PVSM. Ps rows are wave-private
// (own-wave write + own-wave read); the pre-barrier lgkmcnt(0) orders writes
// before next-iter RB. Everything else byte-identical to R16.
// ---------------------------------------------------------------------------
__global__ __launch_bounds__(512) void attn_kernel(
    const unsigned short* __restrict__ qg,
    const unsigned short* __restrict__ kg,
    const unsigned short* __restrict__ vg,
    unsigned short* __restrict__ Op,
    float* __restrict__ Ms, float* __restrict__ Ls)
{
    __shared__ __align__(16) unsigned short Kb[2][64 * 128];   // 16 KB each
    __shared__ __align__(16) unsigned short Vb[3][128 * 64];   // 16 KB each
    __shared__ __align__(16) unsigned short Ps[256 * 64];      // 32 KB wave-priv rows

    const int t = threadIdx.x;                        // 0..511
    const int w = t >> 6, quad = (t >> 4) & 3, l15 = t & 15;

    const int bid = blockIdx.x;                       // 256
    const int swz = ((bid & 7) << 5) | (bid >> 3);    // bijective, 32/XCD chunks
    const int gidx = swz >> 4;            // 0..15 = (b,z) group
    const int b = gidx & 3;
    const int z = gidx >> 2;              // 0..3
    const int i0 = (swz & 15) * 256;
    const int jbase = z * 1024;
    const size_t vbase = (size_t)b * CDIM * NTOT;

    // Q B-fragments direct from global (already LOG2E-scaled by qkv)
    f16x8 bQ[2][4];
    #pragma unroll
    for (int nt = 0; nt < 2; ++nt) {
        const size_t qrow = ((size_t)b * NTOT + i0 + w * 32 + nt * 16 + l15) * CDIM;
        #pragma unroll
        for (int f = 0; f < 4; ++f)
            bQ[nt][f] = *(const f16x8*)&qg[qrow + f * 32 + quad * 8];
    }

    // K tile [64 j][128 c] = 1024 chunks -> 2 per thread (512 thr).
    auto stageK = [&](unsigned short* Kd, int j0) {
        const size_t kbase = ((size_t)b * NTOT + j0) * CDIM;
        #pragma unroll
        for (int r = 0; r < 2; ++r) {
            const int flat = r * 512 + t;
            const int ldsoff = (r * 512 + (t & ~63)) * 8;  // wave-uniform, ush
            const int krow = flat >> 4, kcc = flat & 15;
            gload_lds16(&kg[kbase + (size_t)krow * CDIM + ((kcc ^ (krow & 15)) << 3)],
                        &Kd[ldsoff]);
        }
    };
    // V tile [128 d][64 j] = 1024 chunks -> 2 per thread.
    auto stageV = [&](unsigned short* Vd, int j0) {
        const size_t vrow0 = vbase + j0;
        #pragma unroll
        for (int r = 0; r < 2; ++r) {
            const int flat = r * 512 + t;
            const int ldsoff = (r * 512 + (t & ~63)) * 8;
            const int vrow = flat >> 3, vcc = flat & 7;
            gload_lds16(&vg[vrow0 + (size_t)vrow * NTOT + ((vcc ^ (vrow & 7)) << 3)],
                        &Vd[ldsoff]);
        }
    };

    floatx4 accO[2][8];   // [nt][dt]
    #pragma unroll
    for (int nt = 0; nt < 2; ++nt)
        #pragma unroll
        for (int dt = 0; dt < 8; ++dt) accO[nt][dt] = (floatx4){0.f, 0.f, 0.f, 0.f};
    float m_run[2] = {-INFINITY, -INFINITY};   // log2 domain
    float l_part[2] = {0.f, 0.f};

    floatx4 accT[2][4];
    f16x8 bP[2][2];
    float alpha[2], mcur[2], ps[2];

    auto QK = [&](const unsigned short* Kd) {
        #pragma unroll
        for (int nt = 0; nt < 2; ++nt)
            #pragma unroll
            for (int jt = 0; jt < 4; ++jt) accT[nt][jt] = (floatx4){0.f, 0.f, 0.f, 0.f};
        __builtin_amdgcn_s_setprio(1);
        #pragma unroll
        for (int jt = 0; jt < 4; ++jt)
            #pragma unroll
            for (int f = 0; f < 4; ++f) {
                f16x8 aK = *(const f16x8*)&Kd[SWZ(jt * 16 + l15, f * 4 + quad)];
                accT[0][jt] = mfma16(aK, bQ[0][f], accT[0][jt]);
                accT[1][jt] = mfma16(aK, bQ[1][f], accT[1][jt]);
            }
        __builtin_amdgcn_s_setprio(0);
    };
    auto RB = [&]() {   // read P[i-1] fragments (own rows) early
        #pragma unroll
        for (int nt = 0; nt < 2; ++nt) {
            const int prow = w * 32 + nt * 16 + l15;
            #pragma unroll
            for (int kb = 0; kb < 2; ++kb)
                bP[nt][kb] = *(const f16x8*)&Ps[SWZ8(prow, kb * 4 + quad)];
        }
    };
    // SMpre: per-lane max reduce + alpha (unconditional; =1 when no new max),
    // running-stat updates. Depends only on accT.
    auto SMpre = [&]() {
        ps[0] = 0.f; ps[1] = 0.f;
        #pragma unroll
        for (int nt = 0; nt < 2; ++nt) {
            float tm = accT[nt][0][0];
            #pragma unroll
            for (int jt = 0; jt < 4; ++jt)
                #pragma unroll
                for (int r = 0; r < 4; ++r) tm = fmaxf(tm, accT[nt][jt][r]);
            tm = fmaxf(tm, __shfl_xor(tm, 16));
            tm = fmaxf(tm, __shfl_xor(tm, 32));
            const float mnew = fmaxf(m_run[nt], tm);
            alpha[nt] = fexp2(m_run[nt] - mnew);   // 0 on first tile; 1 if no new max
            m_run[nt] = mnew;
            mcur[nt] = mnew;
            l_part[nt] *= alpha[nt];
        }
    };
    // one branch-free exp/pack slice (snt, sjt) + INLINE P-write (under MFMA
    // shadow when called from PVSM). Own-row write, own-wave read.
    auto SLICE = [&](int snt, int sjt) {
        float p0 = fexp2(accT[snt][sjt][0] - mcur[snt]);
        float p1 = fexp2(accT[snt][sjt][1] - mcur[snt]);
        float p2 = fexp2(accT[snt][sjt][2] - mcur[snt]);
        float p3 = fexp2(accT[snt][sjt][3] - mcur[snt]);
        ps[snt] += (p0 + p1) + (p2 + p3);
        uint2 pw;
        pw.x = __builtin_bit_cast(unsigned int, __builtin_amdgcn_cvt_pkrtz(p0, p1));
        pw.y = __builtin_bit_cast(unsigned int, __builtin_amdgcn_cvt_pkrtz(p2, p3));
        const int prow = w * 32 + snt * 16 + l15;
        *(uint2*)&Ps[SWZ8(prow, 2 * sjt + (quad >> 1)) + (quad & 1) * 4] = pw;
    };
    // fused PV(x)SM: per dt -> 4 PV MFMAs, rescale accO[.][dt], one SLICE
    // (exp/pack + ds_write all under the in-flight MFMAs).
    auto PVSM = [&](const unsigned short* Vd) {
        #pragma unroll
        for (int dt = 0; dt < 8; ++dt) {
            f16x8 aV0 = *(const f16x8*)&Vd[SWZ8(dt * 16 + l15, 0 * 4 + quad)];
            f16x8 aV1 = *(const f16x8*)&Vd[SWZ8(dt * 16 + l15, 1 * 4 + quad)];
            accO[0][dt] = mfma16(aV0, bP[0][0], accO[0][dt]);
            accO[1][dt] = mfma16(aV0, bP[1][0], accO[1][dt]);
            accO[0][dt] = mfma16(aV1, bP[0][1], accO[0][dt]);
            accO[1][dt] = mfma16(aV1, bP[1][1], accO[1][dt]);
            accO[0][dt][0] *= alpha[0]; accO[0][dt][1] *= alpha[0];
            accO[0][dt][2] *= alpha[0]; accO[0][dt][3] *= alpha[0];
            accO[1][dt][0] *= alpha[1]; accO[1][dt][1] *= alpha[1];
            accO[1][dt][2] *= alpha[1]; accO[1][dt][3] *= alpha[1];
            SLICE(dt >> 2, dt & 3);
        }
    };
    auto PVonly = [&](const unsigned short* Vd) {   // epilogue PV, no SM
        #pragma unroll
        for (int dt = 0; dt < 8; ++dt)
            #pragma unroll
            for (int kb = 0; kb < 2; ++kb) {
                f16x8 aV = *(const f16x8*)&Vd[SWZ8(dt * 16 + l15, kb * 4 + quad)];
                accO[0][dt] = mfma16(aV, bP[0][kb], accO[0][dt]);
                accO[1][dt] = mfma16(aV, bP[1][kb], accO[1][dt]);
            }
    };

    stageK(Kb[0], jbase);
    stageV(Vb[0], jbase);
    unsigned short *Kc = Kb[0], *Kn = Kb[1];
    unsigned short *Vprev = Vb[0], *Vcur = Vb[1], *Vnext = Vb[2];

    // ---- iter 0 (peeled): no PV; slices write P inline ----
    asm volatile("s_waitcnt vmcnt(0) lgkmcnt(0)" ::: "memory");
    __builtin_amdgcn_s_barrier();
    stageK(Kn, jbase + 64);
    stageV(Vcur, jbase + 64);     // V[1] -> Vb[1]
    QK(Kc);
    SMpre();
    #pragma unroll
    for (int s = 0; s < 8; ++s) SLICE(s >> 2, s & 3);
    l_part[0] += ps[0]; l_part[1] += ps[1];
    { unsigned short* tp = Kc; Kc = Kn; Kn = tp; }
    // now: Vprev = V[0], Vcur = V[1] (in flight), Vnext = free

    // ---- iters 1..14: ONE barrier per iter ----
    for (int it = 1; it <= 14; ++it) {
        // (A) own K[it] + V[it-1] landed (vmcnt(2): V[it] may still fly) +
        // own LDS ops done; barrier extends to all waves -> V[it-2]'s buffer
        // (Vnext) is dead everywhere, K[it] / V[it-1] tiles complete.
        asm volatile("s_waitcnt vmcnt(2) lgkmcnt(0)" ::: "memory");
        __builtin_amdgcn_s_barrier();
        RB();                                   // P[it-1] (own rows)
        stageK(Kn, jbase + (it + 1) * 64);      // K[it+1]
        stageV(Vnext, jbase + (it + 1) * 64);   // V[it+1] into V[it-2]'s buffer
        QK(Kc);                                 // MFMA: K[it] x Q
        SMpre();                                // VALU: max/alpha (overlaps QK tail)
        PVSM(Vprev);                            // MFMA(PV) x VALU(exp/pack/ds_write)
        l_part[0] += ps[0]; l_part[1] += ps[1];
        { unsigned short* tp = Kc; Kc = Kn; Kn = tp; }
        { unsigned short* tv = Vprev; Vprev = Vcur; Vcur = Vnext; Vnext = tv; }
    }

    // ---- iter 15 (peeled): no staging ----
    asm volatile("s_waitcnt vmcnt(2) lgkmcnt(0)" ::: "memory");
    __builtin_amdgcn_s_barrier();
    RB();
    QK(Kc);
    SMpre();
    PVSM(Vprev);                                // V[14]; slices write pu(15)
    l_part[0] += ps[0]; l_part[1] += ps[1];
    Vprev = Vcur;                               // V[15]
    // epilogue: all waves' V[15] staging landed + own P writes drained
    asm volatile("s_waitcnt vmcnt(0) lgkmcnt(0)" ::: "memory");
    __builtin_amdgcn_s_barrier();
    RB();
    PVonly(Vprev);

    // final l over quads; store normalized partials + stats (Ms in log2 domain)
    #pragma unroll
    for (int nt = 0; nt < 2; ++nt) {
        float lf = l_part[nt];
        lf += __shfl_xor(lf, 16);
        lf += __shfl_xor(lf, 32);
        const float inv = 1.0f / lf;
        const size_t orow =
            (((size_t)z * 4 + b) * NTOT + i0 + w * 32 + nt * 16 + l15) * CDIM;
        #pragma unroll
        for (int dt = 0; dt < 8; ++dt) {
            ushort4 u;
            u.x = f2h(accO[nt][dt][0] * inv); u.y = f2h(accO[nt][dt][1] * inv);
            u.z = f2h(accO[nt][dt][2] * inv); u.w = f2h(accO[nt][dt][3] * inv);
            *(ushort4*)&Op[orow + dt * 16 + quad * 4] = u;
        }
        if (quad == 0) {
            const int idx = (z * 4 + b) * NTOT + i0 + w * 32 + nt * 16 + l15;
            Ms[idx] = m_run[nt];
            Ls[idx] = lf;
        }
    }
}

// ---------------------------------------------------------------------------
// Output projection + residual with FUSED split-K(4) combine (base-2 merge;
// R13-identical).
// ---------------------------------------------------------------------------
__global__ __launch_bounds__(256) void out_proj_kernel(
    const unsigned short* __restrict__ Op,
    const float* __restrict__ Ms, const float* __restrict__ Ls,
    const float* __restrict__ Wo, const float* __restrict__ bo,
    const float* __restrict__ x, float* __restrict__ out)
{
    __shared__ __align__(16) unsigned short As[64][136];  // [n][c] merged
    __shared__ __align__(16) unsigned short Ws[64][136];  // [o-half][c]

    const int t = threadIdx.x, b = blockIdx.y, n0 = blockIdx.x * 64;
    const int zo = blockIdx.z * 64;
    const int w = t >> 6, quad = (t >> 4) & 3, l15 = t & 15;

    const size_t PER = (size_t)NTOT * 4 * CDIM;   // elements per key-quarter

    #pragma unroll
    for (int r = 0; r < 4; ++r) {   // stage merged ao tile
        int flat = r * 256 + t;
        int row = flat >> 4, c16 = (flat & 15) * 8;
        const int bn = b * NTOT + n0 + row;
        float m0 = Ms[bn], m1 = Ms[bn + 16384], m2 = Ms[bn + 32768], m3 = Ms[bn + 49152];
        float M = fmaxf(fmaxf(m0, m1), fmaxf(m2, m3));
        float w0 = Ls[bn]         * fexp2(m0 - M);
        float w1 = Ls[bn + 16384] * fexp2(m1 - M);
        float w2 = Ls[bn + 32768] * fexp2(m2 - M);
        float w3 = Ls[bn + 49152] * fexp2(m3 - M);
        const float inv = 1.0f / (w0 + w1 + w2 + w3);
        w0 *= inv; w1 *= inv; w2 *= inv; w3 *= inv;

        const size_t base = (size_t)bn * CDIM + c16;
        uint4 a0 = *(const uint4*)&Op[base];
        uint4 a1 = *(const uint4*)&Op[PER + base];
        uint4 a2 = *(const uint4*)&Op[2 * PER + base];
        uint4 a3 = *(const uint4*)&Op[3 * PER + base];
        const unsigned short* p0 = (const unsigned short*)&a0;
        const unsigned short* p1 = (const unsigned short*)&a1;
        const unsigned short* p2 = (const unsigned short*)&a2;
        const unsigned short* p3 = (const unsigned short*)&a3;
        unsigned short mv[8];
        #pragma unroll
        for (int j = 0; j < 8; ++j)
            mv[j] = f2h(w0 * h2f(p0[j]) + w1 * h2f(p1[j]) +
                        w2 * h2f(p2[j]) + w3 * h2f(p3[j]));
        *(uint4*)&As[row][c16] = *(const uint4*)mv;
    }
    {
        int o = t >> 2, ch = (t & 3) * 32;
        #pragma unroll
        for (int i = 0; i < 8; ++i) {
            float4 f4 = *(const float4*)&Wo[(size_t)(zo + o) * CDIM + ch + i * 4];
            ushort4 u = { f2h(f4.x), f2h(f4.y), f2h(f4.z), f2h(f4.w) };
            *(ushort4*)&Ws[o][ch + i * 4] = u;
        }
    }
    __syncthreads();

    f16x8 bA[4];
    #pragma unroll
    for (int f = 0; f < 4; ++f)
        bA[f] = *(const f16x8*)&As[w * 16 + l15][f * 32 + quad * 8];

    #pragma unroll
    for (int ot = 0; ot < 4; ++ot) {
        floatx4 acc = (floatx4){0.f, 0.f, 0.f, 0.f};
        #pragma unroll
        for (int f = 0; f < 4; ++f) {
            f16x8 aW = *(const f16x8*)&Ws[ot * 16 + l15][f * 32 + quad * 8];
            acc = mfma16(aW, bA[f], acc);
        }
        const int ob = zo + ot * 16 + quad * 4;
        #pragma unroll
        for (int r = 0; r < 4; ++r) {
            size_t idx = ((size_t)b * CDIM + ob + r) * NTOT + n0 + w * 16 + l15;
            out[idx] = acc[r] + bo[ob + r] + x[idx];
        }
    }
}

// ---------------------------------------------------------------------------
extern "C" void kernel_launch(void* const* d_in, const int* in_sizes, int n_in,
                              void* d_out, int out_size, void* d_ws, size_t ws_size,
                              hipStream_t stream)
{
    const float* x  = (const float*)d_in[0];
    const float* Wq = (const float*)d_in[1];
    const float* bq = (const float*)d_in[2];
    const float* Wk = (const float*)d_in[3];
    const float* bk = (const float*)d_in[4];
    const float* Wv = (const float*)d_in[5];
    const float* bv = (const float*)d_in[6];
    const float* Wo = (const float*)d_in[7];
    const float* bo = (const float*)d_in[8];
    float* out = (float*)d_out;

    const size_t PER = (size_t)4 * CDIM * NTOT;   // 2,097,152 elements
    unsigned short* q_ws  = (unsigned short*)d_ws;
    unsigned short* k_ws  = q_ws + PER;
    unsigned short* v_ws  = k_ws + PER;
    unsigned short* op_ws = v_ws + PER;           // fp16 [4][b][n][c] partials
    float*          ms_ws = (float*)(op_ws + 4 * PER);   // [4][b*n]
    float*          ls_ws = ms_ws + 4 * 16384;

    qkv_proj_kernel<<<dim3(64, 4, 2), dim3(256), 0, stream>>>(
        x, Wq, Wk, Wv, bq, bk, bv, q_ws, k_ws, v_ws);
    attn_kernel<<<dim3(256), dim3(512), 0, stream>>>(
        q_ws, k_ws, v_ws, op_ws, ms_ws, ls_ws);
    out_proj_kernel<<<dim3(64, 4, 2), dim3(256), 0, stream>>>(
        op_ws, ms_ws, ls_ws, Wo, bo, x, out);
}